// Round 3
// baseline (13958.640 us; speedup 1.0000x reference)
//
#include <hip/hip_runtime.h>

#define F_DIM 512
#define H_DIM 2048
#define V_DIM 32000
#define B_DIM 64
#define S_DIM 256
#define ROWS (S_DIM*B_DIM)          // 16384
#define NT_LOG 250                  // 32000/128
#define SCALE 0.04419417382415922f  // 1/sqrt(512)
#define NWORK 32                    // recurrence workers (one XCD's worth of CUs)

typedef __attribute__((ext_vector_type(8))) short  short8;
typedef __attribute__((ext_vector_type(4))) float  floatx4;

static __device__ inline unsigned short f2bf(float x){
  unsigned int u = __float_as_uint(x);
  u += 0x7fffu + ((u >> 16) & 1u);           // RNE
  return (unsigned short)(u >> 16);
}
static __device__ inline float bf2f(unsigned short u){
  return __uint_as_float(((unsigned int)u) << 16);
}
static __device__ inline float wsum(float v){
  #pragma unroll
  for(int m = 32; m > 0; m >>= 1) v += __shfl_xor(v, m);
  return v;
}
static __device__ inline void load_lds16(const void* g, void* l){
  __builtin_amdgcn_global_load_lds((const __attribute__((address_space(1))) void*)g,
                                   (__attribute__((address_space(3))) void*)l, 16, 0, 0);
}

// ---------------- casts ----------------
__global__ __launch_bounds__(256) void cast_w(const float* __restrict__ src,
                                              unsigned short* __restrict__ dst, int n){
  int i = blockIdx.x*256 + threadIdx.x;
  int stride = gridDim.x*256;
  for(; i < n; i += stride) dst[i] = f2bf(src[i]);
}
__global__ __launch_bounds__(256) void cast_emb(const float* __restrict__ src,
                                                unsigned short* __restrict__ dst){
  int i = blockIdx.x*256 + threadIdx.x;
  int stride = gridDim.x*256;
  for(; i < V_DIM*F_DIM; i += stride){
    float v = (i < F_DIM) ? 0.f : src[i];    // PAD row (0) zeroed
    dst[i] = f2bf(v);
  }
}

// ---------------- prep: see^T halves in bf16 ----------------
__global__ __launch_bounds__(256) void prep_see(const float* __restrict__ see,
    unsigned short* __restrict__ TT, unsigned short* __restrict__ BT){
  int n = blockIdx.x;
  for(int k = threadIdx.x; k < 512; k += 256){
    TT[n*512 + k] = f2bf(see[(long)k*512 + n]);
    BT[n*512 + k] = f2bf(see[(long)(512+k)*512 + n]);
  }
}

// ---------------- gather embedding rows per (t,b), bf16; row = t*64+b -------
__global__ __launch_bounds__(256) void gather_vecs(const float* __restrict__ emb,
    const int* __restrict__ inp, unsigned short* __restrict__ V){
  long row = (long)blockIdx.x*4 + (threadIdx.x >> 6);
  int l = threadIdx.x & 63;
  int t = (int)(row >> 6), b = (int)(row & 63);
  int idx = inp[b*S_DIM + t];
  short8 o;
  if (idx == 0){
    #pragma unroll
    for(int i=0;i<8;i++) o[i] = 0;
  } else {
    const float* e = emb + (long)idx*F_DIM + l*8;
    float4 a = *(const float4*)e;
    float4 bq = *(const float4*)(e + 4);
    o[0]=(short)f2bf(a.x); o[1]=(short)f2bf(a.y); o[2]=(short)f2bf(a.z); o[3]=(short)f2bf(a.w);
    o[4]=(short)f2bf(bq.x);o[5]=(short)f2bf(bq.y);o[6]=(short)f2bf(bq.z);o[7]=(short)f2bf(bq.w);
  }
  *(short8*)(V + row*F_DIM + l*8) = o;
}

// ---------------- persistent recurrence, XCD-colocated ----------------
// 256 blocks launched; 32 workers elected on ONE XCD (shared L2).
// Worker rank owns cols [rank*16, rank*16+16). Wave w owns rows w*16..w*16+15.
// ctl[0]=step barrier, ctl[1]=winner(xcd+1, 0=unset), ctl[2..9]=per-XCD tickets.
__global__ __launch_bounds__(256, 1) void recurrence_persistent(
    const unsigned short* __restrict__ VECS,   // [16384,512] bf16
    const float* __restrict__ Z,               // [16384,512] fp32 = vecs@seeTop + bias
    const unsigned short* __restrict__ WBT,    // seeBotT [n=512][k=512] bf16
    unsigned short* __restrict__ CONTB,        // [256][64][512] bf16 state history
    unsigned int* ctl)
{
  __shared__ int s_rank;
  if (threadIdx.x == 0){
    unsigned xcd = __builtin_amdgcn_s_getreg(63508) & 7u;   // HW_REG_XCC_ID
    unsigned tk = __hip_atomic_fetch_add(&ctl[2+xcd], 1u, __ATOMIC_RELAXED, __HIP_MEMORY_SCOPE_AGENT);
    int rank = -1;
    if (tk < NWORK){
      if (tk == NWORK-1){
        unsigned exp = 0u;
        __hip_atomic_compare_exchange_strong(&ctl[1], &exp, xcd+1u,
            __ATOMIC_RELAXED, __ATOMIC_RELAXED, __HIP_MEMORY_SCOPE_AGENT);
      }
      unsigned wv;
      while ((wv = __hip_atomic_load(&ctl[1], __ATOMIC_RELAXED, __HIP_MEMORY_SCOPE_AGENT)) == 0u)
        __builtin_amdgcn_s_sleep(8);
      if (wv == xcd + 1u) rank = (int)tk;
    }
    s_rank = rank;
  }
  __syncthreads();
  const int rank = s_rank;
  if (rank < 0) return;

  const int tid = threadIdx.x;
  const int w = tid >> 6, l = tid & 63;
  const int rl = l & 15, rq = l >> 4;
  const int nb = rank * 16;
  const int col = nb + rl;

  // see_bot^T fragments, persistent in VGPRs: 16 k-steps for our 16 cols
  short8 Bf[16];
  #pragma unroll
  for(int ks=0; ks<16; ks++)
    Bf[ks] = *(const short8*)((const short*)WBT + (long)(nb + rl)*512 + ks*32 + rq*8);

  float s_old[4] = {0.f, 0.f, 0.f, 0.f};

  // preload gate inputs for t=0
  float zc[4]; unsigned short vcs[4];
  #pragma unroll
  for(int r=0;r<4;r++){
    long row = (long)(w*16 + rq*4 + r);
    zc[r]  = Z[row*512 + col];
    vcs[r] = VECS[row*512 + col];
  }

  for(int t = 0; t < S_DIM; t++){
    floatx4 a0 = (floatx4)0.f, a1 = (floatx4)0.f;
    if (t > 0){
      const short* sb = (const short*)CONTB + (long)(t-1)*(64*512);
      short8 Af[16];
      #pragma unroll
      for(int ks=0; ks<16; ks++)
        Af[ks] = *(const short8*)(sb + (long)(w*16 + rl)*512 + ks*32 + rq*8);
      #pragma unroll
      for(int ks=0; ks<8; ks++){
        a0 = __builtin_amdgcn_mfma_f32_16x16x32_bf16(Af[2*ks],   Bf[2*ks],   a0, 0, 0, 0);
        a1 = __builtin_amdgcn_mfma_f32_16x16x32_bf16(Af[2*ks+1], Bf[2*ks+1], a1, 0, 0, 0);
      }
    }
    unsigned short* cw = CONTB + (long)t*(64*512);
    #pragma unroll
    for(int r=0;r<4;r++){
      int b = w*16 + rq*4 + r;
      float z = zc[r] + a0[r] + a1[r];
      float g = 1.f/(1.f + __expf(-z));
      float s = s_old[r]*g + bf2f(vcs[r])*(1.f - g);
      s_old[r] = s;
      cw[b*512 + col] = f2bf(s);
    }
    __threadfence();   // release: drain bf16 state stores (L2-local)
    // prefetch next step's gate inputs; in flight during the barrier wait
    if (t+1 < S_DIM){
      #pragma unroll
      for(int r=0;r<4;r++){
        long row = (long)(t+1)*64 + w*16 + rq*4 + r;
        zc[r]  = Z[row*512 + col];
        vcs[r] = VECS[row*512 + col];
      }
    }
    __syncthreads();
    if (tid == 0){
      __hip_atomic_fetch_add(&ctl[0], 1u, __ATOMIC_RELEASE, __HIP_MEMORY_SCOPE_AGENT);
      unsigned tgt = NWORK*(unsigned)(t+1);
      while (__hip_atomic_load(&ctl[0], __ATOMIC_ACQUIRE, __HIP_MEMORY_SCOPE_AGENT) < tgt)
        __builtin_amdgcn_s_sleep(1);
    }
    __syncthreads();
    __threadfence();   // acquire: invalidate L1 before reading others' state
  }
}

// ---------------- layernorm (bf16 in) + bf16 cast; 1 row per wave ----------------
__global__ __launch_bounds__(256) void ln_kernel(const unsigned short* __restrict__ contb,
    const float* __restrict__ lg, const float* __restrict__ lb,
    unsigned short* __restrict__ xln)
{
  const int wid = threadIdx.x >> 6, l = threadIdx.x & 63;
  const long row = (long)blockIdx.x*4 + wid;
  short8 xv = *(const short8*)(contb + row*F_DIM + l*8);
  float v[8];
  #pragma unroll
  for(int i=0;i<8;i++) v[i] = bf2f((unsigned short)xv[i]);
  float s = 0.f;
  #pragma unroll
  for(int i=0;i<8;i++) s += v[i];
  s = wsum(s);
  float mu = s * (1.f/512.f);
  float q = 0.f;
  #pragma unroll
  for(int i=0;i<8;i++){ float d = v[i]-mu; q += d*d; }
  q = wsum(q);
  float rs = rsqrtf(q*(1.f/512.f) + 1e-5f);
  short8 o;
  #pragma unroll
  for(int i=0;i<8;i++)
    o[i] = (short)f2bf((v[i]-mu)*rs*lg[l*8+i] + lb[l*8+i]);
  *(short8*)(xln + row*F_DIM + l*8) = o;
}

// ---------------- MFMA GEMM: C[M,N] = A[M,K] * B[N,K]^T (both row-major bf16) ----
// MODE 0: +bias, relu, store bf16.  MODE 1: +bias, store bf16.
// MODE 2: scale by 1/sqrt(F), per-row online-softmax partials per 128-col tile.
// MODE 3: +bias, store fp32 (Cf).
template<int MODE>
__global__ __launch_bounds__(256) void gemm_bt(
    const unsigned short* __restrict__ A,
    const unsigned short* __restrict__ Bm,
    const float* __restrict__ bias,
    unsigned short* __restrict__ C,
    float2* __restrict__ part,
    float* __restrict__ Cf,
    int M, int N, int K, int tiles_m, int tiles_n)
{
  __shared__ short As[128*64];
  __shared__ short Bs[128*64];
  __shared__ float sm[2][64][2][2];

  const int bid = blockIdx.x;
  const int mt = bid % tiles_m;
  const int nt = bid / tiles_m;
  const long m0 = (long)mt * 128;
  const long n0 = (long)nt * 128;
  const int tid = threadIdx.x;
  const int l = tid & 63;
  const int wid = tid >> 6;
  const int wr = wid >> 1, wc = wid & 1;
  const int rl = l & 15, rq = l >> 4;

  const short* Ag = (const short*)A + m0 * K;
  const short* Bg = (const short*)Bm + n0 * K;
  const int grow = tid >> 3;   // 0..31
  const int kp = tid & 7;      // 0..7

  floatx4 acc[4][4];
  #pragma unroll
  for(int i=0;i<4;i++)
    #pragma unroll
    for(int j=0;j<4;j++) acc[i][j] = (floatx4)0.f;

  for(int k0 = 0; k0 < K; k0 += 64){
    __syncthreads();
    #pragma unroll
    for(int ro = 0; ro < 128; ro += 32){
      load_lds16(Ag + (long)(ro + grow)*K + k0 + kp*8, (void*)(As + (ro+grow)*64 + kp*8));
      load_lds16(Bg + (long)(ro + grow)*K + k0 + kp*8, (void*)(Bs + (ro+grow)*64 + kp*8));
    }
    __syncthreads();
    #pragma unroll
    for(int kb = 0; kb < 64; kb += 32){
      short8 af[4], bfr[4];
      #pragma unroll
      for(int i=0;i<4;i++) af[i]  = *(const short8*)(As + (wr*64 + i*16 + rl)*64 + kb + rq*8);
      #pragma unroll
      for(int j=0;j<4;j++) bfr[j] = *(const short8*)(Bs + (wc*64 + j*16 + rl)*64 + kb + rq*8);
      #pragma unroll
      for(int i=0;i<4;i++)
        #pragma unroll
        for(int j=0;j<4;j++)
          acc[i][j] = __builtin_amdgcn_mfma_f32_16x16x32_bf16(af[i], bfr[j], acc[i][j], 0, 0, 0);
    }
  }

  const long mb = m0 + wr*64;
  const long nb = n0 + wc*64;
  if (MODE == 0 || MODE == 1 || MODE == 3){
    #pragma unroll
    for(int j=0;j<4;j++){
      float bj = bias[nb + j*16 + rl];
      #pragma unroll
      for(int i=0;i<4;i++){
        #pragma unroll
        for(int r=0;r<4;r++){
          float v = acc[i][j][r] + bj;
          if (MODE == 0) v = fmaxf(v, 0.f);
          if (MODE == 3)
            Cf[(mb + i*16 + rq*4 + r)*N + nb + j*16 + rl] = v;
          else
            C[(mb + i*16 + rq*4 + r)*N + nb + j*16 + rl] = f2bf(v);
        }
      }
    }
  } else {
    #pragma unroll
    for(int i=0;i<4;i++){
      #pragma unroll
      for(int r=0;r<4;r++){
        float mx = -3.4e38f;
        #pragma unroll
        for(int j=0;j<4;j++) mx = fmaxf(mx, acc[i][j][r]);
        #pragma unroll
        for(int d=1; d<16; d<<=1) mx = fmaxf(mx, __shfl_xor(mx, d));
        float ms = mx * SCALE;
        float sv = 0.f;
        #pragma unroll
        for(int j=0;j<4;j++) sv += expf(acc[i][j][r]*SCALE - ms);
        #pragma unroll
        for(int d=1; d<16; d<<=1) sv += __shfl_xor(sv, d);
        if (rl == 0){
          int rowl = i*16 + rq*4 + r;
          sm[wr][rowl][wc][0] = ms;
          sm[wr][rowl][wc][1] = sv;
        }
      }
    }
    __syncthreads();
    if (tid < 128){
      int wr2 = tid >> 6, rowl = tid & 63;
      float ma = sm[wr2][rowl][0][0], sa = sm[wr2][rowl][0][1];
      float mb2= sm[wr2][rowl][1][0], sb = sm[wr2][rowl][1][1];
      float Mn = fmaxf(ma, mb2);
      float Ln = sa*expf(ma - Mn) + sb*expf(mb2 - Mn);
      float2 o; o.x = Mn; o.y = Ln;
      part[(m0 + wr2*64 + rowl)*tiles_n + nt] = o;
    }
  }
}

// ---------------- target logit ----------------
__global__ __launch_bounds__(256) void tlogit_kernel(const unsigned short* __restrict__ outb,
    const unsigned short* __restrict__ embb, const int* __restrict__ tgt,
    float* __restrict__ TL)
{
  long gw = (long)blockIdx.x*4 + (threadIdx.x >> 6);
  int l = threadIdx.x & 63;
  int t = (int)(gw >> 6), b = (int)(gw & 63);
  int tg = tgt[b*S_DIM + t];
  const unsigned short* o = outb + gw*F_DIM;
  const unsigned short* e = embb + (long)tg*F_DIM;
  short8 ov = *(const short8*)(o + l*8);
  short8 ev = *(const short8*)(e + l*8);
  float s = 0.f;
  #pragma unroll
  for(int i=0;i<8;i++) s += bf2f((unsigned short)ov[i]) * bf2f((unsigned short)ev[i]);
  s = wsum(s);
  if (l == 0) TL[gw] = s * SCALE;
}

// ---------------- merge partials -> nll ----------------
__global__ __launch_bounds__(256) void lse_kernel(const float2* __restrict__ part,
    const float* __restrict__ TL, float* __restrict__ nll)
{
  long row = (long)blockIdx.x*4 + (threadIdx.x >> 6);
  int l = threadIdx.x & 63;
  float M = -3.4e38f, L = 0.f;
  for(int c = l; c < NT_LOG; c += 64){
    float2 pv = part[row*NT_LOG + c];
    float Mn = fmaxf(M, pv.x);
    L = L*expf(M - Mn) + pv.y*expf(pv.x - Mn);
    M = Mn;
  }
  #pragma unroll
  for(int d=1; d<64; d<<=1){
    float Mo = __shfl_xor(M, d), Lo = __shfl_xor(L, d);
    float Mn = fmaxf(M, Mo);
    L = L*expf(M - Mn) + Lo*expf(Mo - Mn);
    M = Mn;
  }
  if (l == 0) nll[row] = (M + logf(L)) - TL[row];
}

// ---------------- final loss ----------------
__global__ __launch_bounds__(256) void loss_kernel(const float* __restrict__ nll,
    const int* __restrict__ tgt, float* __restrict__ out)
{
  int t = threadIdx.x;
  float s = 0.f; int cnt = 0;
  for(int b = 0; b < B_DIM; b++){
    int v = tgt[b*S_DIM + t];
    if (v != 0){ s += nll[(long)t*B_DIM + b]; cnt++; }
  }
  float li = s / fmaxf((float)cnt, 1.f);
  li = wsum(li);
  __shared__ float red[4];
  if ((t & 63) == 0) red[t >> 6] = li;
  __syncthreads();
  if (t == 0) out[0] = (red[0]+red[1]+red[2]+red[3]) * (1.f/256.f);
}

extern "C" void kernel_launch(void* const* d_in, const int* in_sizes, int n_in,
                              void* d_out, int out_size, void* d_ws, size_t ws_size,
                              hipStream_t stream)
{
  const int*   inp   = (const int*)d_in[0];
  const int*   tgt   = (const int*)d_in[1];
  const float* see   = (const float*)d_in[2];
  const float* bias  = (const float*)d_in[3];
  const float* W_in  = (const float*)d_in[4];
  const float* b_in  = (const float*)d_in[5];
  const float* W_out = (const float*)d_in[6];
  const float* b_out = (const float*)d_in[7];
  const float* ln_g  = (const float*)d_in[8];
  const float* ln_b  = (const float*)d_in[9];
  const float* emb   = (const float*)d_in[10];

  char* p = (char*)d_ws;
  unsigned short* CONTB= (unsigned short*)p; p += (size_t)ROWS*F_DIM*2;   // 16.8 MB
  unsigned short* XLN  = (unsigned short*)p; p += (size_t)ROWS*F_DIM*2;   // 16.8 MB
  unsigned short* Hb   = (unsigned short*)p; p += (size_t)ROWS*H_DIM*2;   // 67.1 MB
  unsigned short* OUTb = (unsigned short*)p; p += (size_t)ROWS*F_DIM*2;   // 16.8 MB
  unsigned short* EMBb = (unsigned short*)p; p += (size_t)V_DIM*F_DIM*2;  // 32.8 MB
  unsigned short* WINb = (unsigned short*)p; p += (size_t)H_DIM*F_DIM*2;  //  2.1 MB
  unsigned short* WOUTb= (unsigned short*)p; p += (size_t)F_DIM*H_DIM*2;  //  2.1 MB
  float2* PART         = (float2*)p;         p += (size_t)ROWS*NT_LOG*8;  // 32.8 MB
  float* TL            = (float*)p;          p += (size_t)ROWS*4;
  float* NLL           = (float*)p;          p += (size_t)ROWS*4;
  unsigned short* VECSb= (unsigned short*)p; p += (size_t)ROWS*F_DIM*2;   // 16.8 MB
  float* Zf            = (float*)p;          p += (size_t)ROWS*F_DIM*4;   // 33.6 MB
  unsigned short* SEETT= (unsigned short*)p; p += (size_t)F_DIM*F_DIM*2;  //  0.5 MB
  unsigned short* SEEBT= (unsigned short*)p; p += (size_t)F_DIM*F_DIM*2;  //  0.5 MB
  unsigned int* CTL    = (unsigned int*)p;   p += 256;

  // independent prep
  cast_emb<<<4096, 256, 0, stream>>>(emb, EMBb);
  cast_w<<<2048, 256, 0, stream>>>(W_in,  WINb,  H_DIM*F_DIM);
  cast_w<<<2048, 256, 0, stream>>>(W_out, WOUTb, F_DIM*H_DIM);
  prep_see<<<512, 256, 0, stream>>>(see, SEETT, SEEBT);
  gather_vecs<<<ROWS/4, 256, 0, stream>>>(emb, inp, VECSb);

  // Z = vecs @ see_top + bias  (fp32 out)
  gemm_bt<3><<<128*4, 256, 0, stream>>>(VECSb, SEETT, bias, nullptr, nullptr, Zf,
                                        ROWS, F_DIM, F_DIM, 128, 4);

  // persistent recurrence (XCD-colocated workers)
  hipMemsetAsync(CTL, 0, 256, stream);
  recurrence_persistent<<<256, 256, 0, stream>>>(VECSb, Zf, SEEBT, CONTB, CTL);

  // downstream
  ln_kernel<<<ROWS/4, 256, 0, stream>>>(CONTB, ln_g, ln_b, XLN);
  gemm_bt<0><<<128*16, 256, 0, stream>>>(XLN,  WINb,  b_in,  Hb,   nullptr, nullptr, ROWS, H_DIM, F_DIM, 128, 16);
  gemm_bt<1><<<128*4,  256, 0, stream>>>(Hb,   WOUTb, b_out, OUTb, nullptr, nullptr, ROWS, F_DIM, H_DIM, 128, 4);
  tlogit_kernel<<<ROWS/4, 256, 0, stream>>>(OUTb, EMBb, tgt, TL);
  gemm_bt<2><<<128*NT_LOG, 256, 0, stream>>>(OUTb, EMBb, nullptr, nullptr, PART, nullptr, ROWS, V_DIM, F_DIM, 128, NT_LOG);
  lse_kernel<<<ROWS/4, 256, 0, stream>>>(PART, TL, NLL);
  loss_kernel<<<1, 256, 0, stream>>>(NLL, tgt, (float*)d_out);
}

// Round 4
// 3859.774 us; speedup vs baseline: 3.6164x; 3.6164x over previous
//
#include <hip/hip_runtime.h>

#define F_DIM 512
#define H_DIM 2048
#define V_DIM 32000
#define B_DIM 64
#define S_DIM 256
#define ROWS (S_DIM*B_DIM)          // 16384
#define NT_LOG 250                  // 32000/128
#define SCALE 0.04419417382415922f  // 1/sqrt(512)

typedef __attribute__((ext_vector_type(8))) short  short8;
typedef __attribute__((ext_vector_type(4))) float  floatx4;

static __device__ inline unsigned short f2bf(float x){
  unsigned int u = __float_as_uint(x);
  u += 0x7fffu + ((u >> 16) & 1u);           // RNE
  return (unsigned short)(u >> 16);
}
static __device__ inline float bf2f(unsigned short u){
  return __uint_as_float(((unsigned int)u) << 16);
}
static __device__ inline float wsum(float v){
  #pragma unroll
  for(int m = 32; m > 0; m >>= 1) v += __shfl_xor(v, m);
  return v;
}
static __device__ inline void load_lds16(const void* g, void* l){
  __builtin_amdgcn_global_load_lds((const __attribute__((address_space(1))) void*)g,
                                   (__attribute__((address_space(3))) void*)l, 16, 0, 0);
}

// ---------------- casts ----------------
__global__ __launch_bounds__(256) void cast_w(const float* __restrict__ src,
                                              unsigned short* __restrict__ dst, int n){
  int i = blockIdx.x*256 + threadIdx.x;
  int stride = gridDim.x*256;
  for(; i < n; i += stride) dst[i] = f2bf(src[i]);
}
__global__ __launch_bounds__(256) void cast_emb(const float* __restrict__ src,
                                                unsigned short* __restrict__ dst){
  int i = blockIdx.x*256 + threadIdx.x;
  int stride = gridDim.x*256;
  for(; i < V_DIM*F_DIM; i += stride){
    float v = (i < F_DIM) ? 0.f : src[i];    // PAD row (0) zeroed
    dst[i] = f2bf(v);
  }
}

// ---------------- prep: see^T halves in bf16 ----------------
__global__ __launch_bounds__(256) void prep_see(const float* __restrict__ see,
    unsigned short* __restrict__ TT, unsigned short* __restrict__ BT){
  int n = blockIdx.x;
  for(int k = threadIdx.x; k < 512; k += 256){
    TT[n*512 + k] = f2bf(see[(long)k*512 + n]);
    BT[n*512 + k] = f2bf(see[(long)(512+k)*512 + n]);
  }
}

// ---------------- gather embedding rows per (t,b), bf16; row = t*64+b -------
__global__ __launch_bounds__(256) void gather_vecs(const float* __restrict__ emb,
    const int* __restrict__ inp, unsigned short* __restrict__ V){
  long row = (long)blockIdx.x*4 + (threadIdx.x >> 6);
  int l = threadIdx.x & 63;
  int t = (int)(row >> 6), b = (int)(row & 63);
  int idx = inp[b*S_DIM + t];
  short8 o;
  if (idx == 0){
    #pragma unroll
    for(int i=0;i<8;i++) o[i] = 0;
  } else {
    const float* e = emb + (long)idx*F_DIM + l*8;
    float4 a = *(const float4*)e;
    float4 bq = *(const float4*)(e + 4);
    o[0]=(short)f2bf(a.x); o[1]=(short)f2bf(a.y); o[2]=(short)f2bf(a.z); o[3]=(short)f2bf(a.w);
    o[4]=(short)f2bf(bq.x);o[5]=(short)f2bf(bq.y);o[6]=(short)f2bf(bq.z);o[7]=(short)f2bf(bq.w);
  }
  *(short8*)(V + row*F_DIM + l*8) = o;
}

// ---------------- batch-parallel recurrence: ZERO inter-block sync ----------
// 4 WGs x 512 thr (8 waves). WG wg owns batch rows wg*16..wg*16+15 for all 256
// steps. Wave w owns output cols [w*64, w*64+64): its see_bot^T fragments
// (64x512 bf16 = 256 VGPRs) are loop-invariant. State: LDS, double-buffered
// bf16 [16][520] (520-short stride: 16B-aligned rows, 2-way bank alias = free).
// One __syncthreads per step. No fences, no atomics.
__global__ __launch_bounds__(512, 1) void recurrence_batch(
    const unsigned short* __restrict__ VECS,   // [16384,512] bf16
    const float* __restrict__ Z,               // [16384,512] fp32 = vecs@seeTop + bias
    const unsigned short* __restrict__ WBT,    // seeBotT [n=512][k=512] bf16
    unsigned short* __restrict__ CONTB)        // [256][64][512] bf16 state history
{
  __shared__ short stt[2][16][520];

  const int tid = threadIdx.x;
  const int w  = tid >> 6;       // wave 0..7 -> cols w*64..
  const int l  = tid & 63;
  const int rl = l & 15, rq = l >> 4;
  const int wg = blockIdx.x;     // batch rows wg*16..
  const int colb = w*64;

  // persistent B fragments: [k-chunk][n-tile]
  short8 Bfr[16][4];
  #pragma unroll
  for(int c=0;c<16;c++)
    #pragma unroll
    for(int tl=0;tl<4;tl++)
      Bfr[c][tl] = *(const short8*)((const short*)WBT
                     + (long)(colb + tl*16 + rl)*512 + c*32 + rq*8);

  float s_old[16];
  #pragma unroll
  for(int i=0;i<16;i++) s_old[i] = 0.f;

  // gate inputs for t=0 (lane owns (m=rq*4+r, col=colb+tl*16+rl))
  float zc[16]; unsigned short vc[16];
  #pragma unroll
  for(int tl=0;tl<4;tl++)
    #pragma unroll
    for(int r=0;r<4;r++){
      long row = (long)(wg*16 + rq*4 + r);
      int col = colb + tl*16 + rl;
      zc[tl*4+r] = Z[row*512 + col];
      vc[tl*4+r] = VECS[row*512 + col];
    }

  for(int t = 0; t < S_DIM; t++){
    __syncthreads();   // state[t-1] writes visible; prev reads done

    floatx4 acc[4];
    #pragma unroll
    for(int tl=0;tl<4;tl++) acc[tl] = (floatx4)0.f;

    if (t > 0){
      const int pb = (t-1)&1;
      #pragma unroll
      for(int c=0;c<16;c++){
        short8 a = *(const short8*)&stt[pb][rl][c*32 + rq*8];
        #pragma unroll
        for(int tl=0;tl<4;tl++)
          acc[tl] = __builtin_amdgcn_mfma_f32_16x16x32_bf16(a, Bfr[c][tl], acc[tl], 0, 0, 0);
      }
    }

    // prefetch next step's gate inputs (overlaps MFMA waitcnt + next barrier)
    float zn[16]; unsigned short vn[16];
    if (t+1 < S_DIM){
      #pragma unroll
      for(int tl=0;tl<4;tl++)
        #pragma unroll
        for(int r=0;r<4;r++){
          long row = (long)(t+1)*64 + wg*16 + rq*4 + r;
          int col = colb + tl*16 + rl;
          zn[tl*4+r] = Z[row*512 + col];
          vn[tl*4+r] = VECS[row*512 + col];
        }
    }

    // gate + state update
    unsigned short* cw = CONTB + ((long)t*64 + wg*16)*512;
    const int cb = t&1;
    #pragma unroll
    for(int tl=0;tl<4;tl++)
      #pragma unroll
      for(int r=0;r<4;r++){
        int m = rq*4 + r;
        int col = colb + tl*16 + rl;
        float z = zc[tl*4+r] + acc[tl][r];
        float g = 1.f/(1.f + __expf(-z));
        float s = s_old[tl*4+r]*g + bf2f(vc[tl*4+r])*(1.f - g);
        s_old[tl*4+r] = s;
        unsigned short sb = f2bf(s);
        stt[cb][m][col] = (short)sb;
        cw[(long)m*512 + col] = sb;
      }

    #pragma unroll
    for(int i=0;i<16;i++){ zc[i] = zn[i]; vc[i] = vn[i]; }
  }
}

// ---------------- layernorm (bf16 in) + bf16 cast; 1 row per wave ----------------
__global__ __launch_bounds__(256) void ln_kernel(const unsigned short* __restrict__ contb,
    const float* __restrict__ lg, const float* __restrict__ lb,
    unsigned short* __restrict__ xln)
{
  const int wid = threadIdx.x >> 6, l = threadIdx.x & 63;
  const long row = (long)blockIdx.x*4 + wid;
  short8 xv = *(const short8*)(contb + row*F_DIM + l*8);
  float v[8];
  #pragma unroll
  for(int i=0;i<8;i++) v[i] = bf2f((unsigned short)xv[i]);
  float s = 0.f;
  #pragma unroll
  for(int i=0;i<8;i++) s += v[i];
  s = wsum(s);
  float mu = s * (1.f/512.f);
  float q = 0.f;
  #pragma unroll
  for(int i=0;i<8;i++){ float d = v[i]-mu; q += d*d; }
  q = wsum(q);
  float rs = rsqrtf(q*(1.f/512.f) + 1e-5f);
  short8 o;
  #pragma unroll
  for(int i=0;i<8;i++)
    o[i] = (short)f2bf((v[i]-mu)*rs*lg[l*8+i] + lb[l*8+i]);
  *(short8*)(xln + row*F_DIM + l*8) = o;
}

// ---------------- MFMA GEMM: C[M,N] = A[M,K] * B[N,K]^T (both row-major bf16) ----
// MODE 0: +bias, relu, store bf16.  MODE 1: +bias, store bf16.
// MODE 2: scale by 1/sqrt(F), per-row online-softmax partials per 128-col tile.
// MODE 3: +bias, store fp32 (Cf).
template<int MODE>
__global__ __launch_bounds__(256) void gemm_bt(
    const unsigned short* __restrict__ A,
    const unsigned short* __restrict__ Bm,
    const float* __restrict__ bias,
    unsigned short* __restrict__ C,
    float2* __restrict__ part,
    float* __restrict__ Cf,
    int M, int N, int K, int tiles_m, int tiles_n)
{
  __shared__ short As[128*64];
  __shared__ short Bs[128*64];
  __shared__ float sm[2][64][2][2];

  const int bid = blockIdx.x;
  const int mt = bid % tiles_m;
  const int nt = bid / tiles_m;
  const long m0 = (long)mt * 128;
  const long n0 = (long)nt * 128;
  const int tid = threadIdx.x;
  const int l = tid & 63;
  const int wid = tid >> 6;
  const int wr = wid >> 1, wc = wid & 1;
  const int rl = l & 15, rq = l >> 4;

  const short* Ag = (const short*)A + m0 * K;
  const short* Bg = (const short*)Bm + n0 * K;
  const int grow = tid >> 3;   // 0..31
  const int kp = tid & 7;      // 0..7

  floatx4 acc[4][4];
  #pragma unroll
  for(int i=0;i<4;i++)
    #pragma unroll
    for(int j=0;j<4;j++) acc[i][j] = (floatx4)0.f;

  for(int k0 = 0; k0 < K; k0 += 64){
    __syncthreads();
    #pragma unroll
    for(int ro = 0; ro < 128; ro += 32){
      load_lds16(Ag + (long)(ro + grow)*K + k0 + kp*8, (void*)(As + (ro+grow)*64 + kp*8));
      load_lds16(Bg + (long)(ro + grow)*K + k0 + kp*8, (void*)(Bs + (ro+grow)*64 + kp*8));
    }
    __syncthreads();
    #pragma unroll
    for(int kb = 0; kb < 64; kb += 32){
      short8 af[4], bfr[4];
      #pragma unroll
      for(int i=0;i<4;i++) af[i]  = *(const short8*)(As + (wr*64 + i*16 + rl)*64 + kb + rq*8);
      #pragma unroll
      for(int j=0;j<4;j++) bfr[j] = *(const short8*)(Bs + (wc*64 + j*16 + rl)*64 + kb + rq*8);
      #pragma unroll
      for(int i=0;i<4;i++)
        #pragma unroll
        for(int j=0;j<4;j++)
          acc[i][j] = __builtin_amdgcn_mfma_f32_16x16x32_bf16(af[i], bfr[j], acc[i][j], 0, 0, 0);
    }
  }

  const long mb = m0 + wr*64;
  const long nb = n0 + wc*64;
  if (MODE == 0 || MODE == 1 || MODE == 3){
    #pragma unroll
    for(int j=0;j<4;j++){
      float bj = bias[nb + j*16 + rl];
      #pragma unroll
      for(int i=0;i<4;i++){
        #pragma unroll
        for(int r=0;r<4;r++){
          float v = acc[i][j][r] + bj;
          if (MODE == 0) v = fmaxf(v, 0.f);
          if (MODE == 3)
            Cf[(mb + i*16 + rq*4 + r)*N + nb + j*16 + rl] = v;
          else
            C[(mb + i*16 + rq*4 + r)*N + nb + j*16 + rl] = f2bf(v);
        }
      }
    }
  } else {
    #pragma unroll
    for(int i=0;i<4;i++){
      #pragma unroll
      for(int r=0;r<4;r++){
        float mx = -3.4e38f;
        #pragma unroll
        for(int j=0;j<4;j++) mx = fmaxf(mx, acc[i][j][r]);
        #pragma unroll
        for(int d=1; d<16; d<<=1) mx = fmaxf(mx, __shfl_xor(mx, d));
        float ms = mx * SCALE;
        float sv = 0.f;
        #pragma unroll
        for(int j=0;j<4;j++) sv += expf(acc[i][j][r]*SCALE - ms);
        #pragma unroll
        for(int d=1; d<16; d<<=1) sv += __shfl_xor(sv, d);
        if (rl == 0){
          int rowl = i*16 + rq*4 + r;
          sm[wr][rowl][wc][0] = ms;
          sm[wr][rowl][wc][1] = sv;
        }
      }
    }
    __syncthreads();
    if (tid < 128){
      int wr2 = tid >> 6, rowl = tid & 63;
      float ma = sm[wr2][rowl][0][0], sa = sm[wr2][rowl][0][1];
      float mb2= sm[wr2][rowl][1][0], sb = sm[wr2][rowl][1][1];
      float Mn = fmaxf(ma, mb2);
      float Ln = sa*expf(ma - Mn) + sb*expf(mb2 - Mn);
      float2 o; o.x = Mn; o.y = Ln;
      part[(m0 + wr2*64 + rowl)*tiles_n + nt] = o;
    }
  }
}

// ---------------- target logit ----------------
__global__ __launch_bounds__(256) void tlogit_kernel(const unsigned short* __restrict__ outb,
    const unsigned short* __restrict__ embb, const int* __restrict__ tgt,
    float* __restrict__ TL)
{
  long gw = (long)blockIdx.x*4 + (threadIdx.x >> 6);
  int l = threadIdx.x & 63;
  int t = (int)(gw >> 6), b = (int)(gw & 63);
  int tg = tgt[b*S_DIM + t];
  const unsigned short* o = outb + gw*F_DIM;
  const unsigned short* e = embb + (long)tg*F_DIM;
  short8 ov = *(const short8*)(o + l*8);
  short8 ev = *(const short8*)(e + l*8);
  float s = 0.f;
  #pragma unroll
  for(int i=0;i<8;i++) s += bf2f((unsigned short)ov[i]) * bf2f((unsigned short)ev[i]);
  s = wsum(s);
  if (l == 0) TL[gw] = s * SCALE;
}

// ---------------- merge partials -> nll ----------------
__global__ __launch_bounds__(256) void lse_kernel(const float2* __restrict__ part,
    const float* __restrict__ TL, float* __restrict__ nll)
{
  long row = (long)blockIdx.x*4 + (threadIdx.x >> 6);
  int l = threadIdx.x & 63;
  float M = -3.4e38f, L = 0.f;
  for(int c = l; c < NT_LOG; c += 64){
    float2 pv = part[row*NT_LOG + c];
    float Mn = fmaxf(M, pv.x);
    L = L*expf(M - Mn) + pv.y*expf(pv.x - Mn);
    M = Mn;
  }
  #pragma unroll
  for(int d=1; d<64; d<<=1){
    float Mo = __shfl_xor(M, d), Lo = __shfl_xor(L, d);
    float Mn = fmaxf(M, Mo);
    L = L*expf(M - Mn) + Lo*expf(Mo - Mn);
    M = Mn;
  }
  if (l == 0) nll[row] = (M + logf(L)) - TL[row];
}

// ---------------- final loss ----------------
__global__ __launch_bounds__(256) void loss_kernel(const float* __restrict__ nll,
    const int* __restrict__ tgt, float* __restrict__ out)
{
  int t = threadIdx.x;
  float s = 0.f; int cnt = 0;
  for(int b = 0; b < B_DIM; b++){
    int v = tgt[b*S_DIM + t];
    if (v != 0){ s += nll[(long)t*B_DIM + b]; cnt++; }
  }
  float li = s / fmaxf((float)cnt, 1.f);
  li = wsum(li);
  __shared__ float red[4];
  if ((t & 63) == 0) red[t >> 6] = li;
  __syncthreads();
  if (t == 0) out[0] = (red[0]+red[1]+red[2]+red[3]) * (1.f/256.f);
}

extern "C" void kernel_launch(void* const* d_in, const int* in_sizes, int n_in,
                              void* d_out, int out_size, void* d_ws, size_t ws_size,
                              hipStream_t stream)
{
  const int*   inp   = (const int*)d_in[0];
  const int*   tgt   = (const int*)d_in[1];
  const float* see   = (const float*)d_in[2];
  const float* bias  = (const float*)d_in[3];
  const float* W_in  = (const float*)d_in[4];
  const float* b_in  = (const float*)d_in[5];
  const float* W_out = (const float*)d_in[6];
  const float* b_out = (const float*)d_in[7];
  const float* ln_g  = (const float*)d_in[8];
  const float* ln_b  = (const float*)d_in[9];
  const float* emb   = (const float*)d_in[10];

  char* p = (char*)d_ws;
  unsigned short* CONTB= (unsigned short*)p; p += (size_t)ROWS*F_DIM*2;   // 16.8 MB
  unsigned short* XLN  = (unsigned short*)p; p += (size_t)ROWS*F_DIM*2;   // 16.8 MB
  unsigned short* Hb   = (unsigned short*)p; p += (size_t)ROWS*H_DIM*2;   // 67.1 MB
  unsigned short* OUTb = (unsigned short*)p; p += (size_t)ROWS*F_DIM*2;   // 16.8 MB
  unsigned short* EMBb = (unsigned short*)p; p += (size_t)V_DIM*F_DIM*2;  // 32.8 MB
  unsigned short* WINb = (unsigned short*)p; p += (size_t)H_DIM*F_DIM*2;  //  2.1 MB
  unsigned short* WOUTb= (unsigned short*)p; p += (size_t)F_DIM*H_DIM*2;  //  2.1 MB
  float2* PART         = (float2*)p;         p += (size_t)ROWS*NT_LOG*8;  // 32.8 MB
  float* TL            = (float*)p;          p += (size_t)ROWS*4;
  float* NLL           = (float*)p;          p += (size_t)ROWS*4;
  unsigned short* VECSb= (unsigned short*)p; p += (size_t)ROWS*F_DIM*2;   // 16.8 MB
  float* Zf            = (float*)p;          p += (size_t)ROWS*F_DIM*4;   // 33.6 MB
  unsigned short* SEETT= (unsigned short*)p; p += (size_t)F_DIM*F_DIM*2;  //  0.5 MB
  unsigned short* SEEBT= (unsigned short*)p; p += (size_t)F_DIM*F_DIM*2;  //  0.5 MB

  // independent prep
  cast_emb<<<4096, 256, 0, stream>>>(emb, EMBb);
  cast_w<<<2048, 256, 0, stream>>>(W_in,  WINb,  H_DIM*F_DIM);
  cast_w<<<2048, 256, 0, stream>>>(W_out, WOUTb, F_DIM*H_DIM);
  prep_see<<<512, 256, 0, stream>>>(see, SEETT, SEEBT);
  gather_vecs<<<ROWS/4, 256, 0, stream>>>(emb, inp, VECSb);

  // Z = vecs @ see_top + bias  (fp32 out)
  gemm_bt<3><<<128*4, 256, 0, stream>>>(VECSb, SEETT, bias, nullptr, nullptr, Zf,
                                        ROWS, F_DIM, F_DIM, 128, 4);

  // batch-parallel recurrence: 4 WGs, no inter-block sync
  recurrence_batch<<<4, 512, 0, stream>>>(VECSb, Zf, SEEBT, CONTB);

  // downstream
  ln_kernel<<<ROWS/4, 256, 0, stream>>>(CONTB, ln_g, ln_b, XLN);
  gemm_bt<0><<<128*16, 256, 0, stream>>>(XLN,  WINb,  b_in,  Hb,   nullptr, nullptr, ROWS, H_DIM, F_DIM, 128, 16);
  gemm_bt<1><<<128*4,  256, 0, stream>>>(Hb,   WOUTb, b_out, OUTb, nullptr, nullptr, ROWS, F_DIM, H_DIM, 128, 4);
  tlogit_kernel<<<ROWS/4, 256, 0, stream>>>(OUTb, EMBb, tgt, TL);
  gemm_bt<2><<<128*NT_LOG, 256, 0, stream>>>(OUTb, EMBb, nullptr, nullptr, PART, nullptr, ROWS, V_DIM, F_DIM, 128, NT_LOG);
  lse_kernel<<<ROWS/4, 256, 0, stream>>>(PART, TL, NLL);
  loss_kernel<<<1, 256, 0, stream>>>(NLL, tgt, (float*)d_out);
}

// Round 5
// 2268.971 us; speedup vs baseline: 6.1520x; 1.7011x over previous
//
#include <hip/hip_runtime.h>
#include <hip/hip_fp8.h>

#define F_DIM 512
#define H_DIM 2048
#define V_DIM 32000
#define B_DIM 64
#define S_DIM 256
#define ROWS (S_DIM*B_DIM)          // 16384
#define NT_LOG 250                  // 32000/128
#define SCALE 0.04419417382415922f  // 1/sqrt(512)

typedef __attribute__((ext_vector_type(8))) short  short8;
typedef __attribute__((ext_vector_type(4))) float  floatx4;

static __device__ inline unsigned short f2bf(float x){
  unsigned int u = __float_as_uint(x);
  u += 0x7fffu + ((u >> 16) & 1u);           // RNE
  return (unsigned short)(u >> 16);
}
static __device__ inline float bf2f(unsigned short u){
  return __uint_as_float(((unsigned int)u) << 16);
}
static __device__ inline float wsum(float v){
  #pragma unroll
  for(int m = 32; m > 0; m >>= 1) v += __shfl_xor(v, m);
  return v;
}
static __device__ inline void load_lds16(const void* g, void* l){
  __builtin_amdgcn_global_load_lds((const __attribute__((address_space(1))) void*)g,
                                   (__attribute__((address_space(3))) void*)l, 16, 0, 0);
}

// ---------------- casts ----------------
__global__ __launch_bounds__(256) void cast_w(const float* __restrict__ src,
                                              unsigned short* __restrict__ dst, int n){
  int i = blockIdx.x*256 + threadIdx.x;
  int stride = gridDim.x*256;
  for(; i < n; i += stride) dst[i] = f2bf(src[i]);
}
__global__ __launch_bounds__(256) void cast_emb(const float* __restrict__ src,
                                                unsigned short* __restrict__ dst){
  int i = blockIdx.x*256 + threadIdx.x;
  int stride = gridDim.x*256;
  for(; i < V_DIM*F_DIM; i += stride){
    float v = (i < F_DIM) ? 0.f : src[i];    // PAD row (0) zeroed
    dst[i] = f2bf(v);
  }
}

// ---------------- prep: see_top^T bf16 (for Z gemm) + see_bot^T fp8 ----------
// TT[n*512+k] = bf16(see[k*512+n]);  B8[n*512+k] = e4m3(see[(512+k)*512+n])
__global__ __launch_bounds__(256) void prep_see(const float* __restrict__ see,
    unsigned short* __restrict__ TT, unsigned char* __restrict__ B8){
  int n = blockIdx.x;
  for(int k = threadIdx.x; k < 512; k += 256){
    TT[n*512 + k] = f2bf(see[(long)k*512 + n]);
    __hip_fp8_e4m3 q(see[(long)(512+k)*512 + n]);
    B8[n*512 + k] = q.__x;
  }
}

// ---------------- gather embedding rows per (t,b), bf16; row = t*64+b -------
__global__ __launch_bounds__(256) void gather_vecs(const float* __restrict__ emb,
    const int* __restrict__ inp, unsigned short* __restrict__ V){
  long row = (long)blockIdx.x*4 + (threadIdx.x >> 6);
  int l = threadIdx.x & 63;
  int t = (int)(row >> 6), b = (int)(row & 63);
  int idx = inp[b*S_DIM + t];
  short8 o;
  if (idx == 0){
    #pragma unroll
    for(int i=0;i<8;i++) o[i] = 0;
  } else {
    const float* e = emb + (long)idx*F_DIM + l*8;
    float4 a = *(const float4*)e;
    float4 bq = *(const float4*)(e + 4);
    o[0]=(short)f2bf(a.x); o[1]=(short)f2bf(a.y); o[2]=(short)f2bf(a.z); o[3]=(short)f2bf(a.w);
    o[4]=(short)f2bf(bq.x);o[5]=(short)f2bf(bq.y);o[6]=(short)f2bf(bq.z);o[7]=(short)f2bf(bq.w);
  }
  *(short8*)(V + row*F_DIM + l*8) = o;
}

// ---------------- pack gate inputs: ZV = (vec_bf16 << 16) | z_bf16 ----------
__global__ __launch_bounds__(256) void pack_zv(const unsigned short* __restrict__ Zb,
    const unsigned short* __restrict__ V, unsigned int* __restrict__ ZV){
  int i = blockIdx.x*256 + threadIdx.x;
  int stride = gridDim.x*256;
  for(; i < ROWS*F_DIM; i += stride)
    ZV[i] = ((unsigned)V[i] << 16) | (unsigned)Zb[i];
}

// ---------------- batch-parallel recurrence, fp8-resident weights ----------
// 4 WGs x 512 thr (8 waves). WG wg owns batch rows wg*16..+15 for all 256
// steps. Wave w owns output cols [w*64, w*64+64): its see_bot^T fp8 fragments
// = long Bfr[16][4] = 128 VGPRs, loop-invariant (fits under the 256-VGPR cap
// at 2 waves/SIMD — bf16 needed 256 and the allocator refused: r2/r4 lesson).
// State history: fp8 in LDS double buffer [16][520B]; s_old stays fp32 in
// registers; bf16 history to global for downstream LN. Zero inter-block sync.
__global__ __launch_bounds__(512, 1) void recurrence_batch(
    const unsigned int* __restrict__ ZV,       // [16384,512] (vec<<16)|z  bf16 pair
    const unsigned char* __restrict__ W8,      // seeBotT fp8 [n=512][k=512]
    unsigned short* __restrict__ CONTB)        // [256][64][512] bf16 state history
{
  __shared__ unsigned char stt[2][16][520];    // 520 = 8B-aligned pad

  const int tid = threadIdx.x;
  const int w  = tid >> 6;       // wave 0..7 -> cols w*64..
  const int l  = tid & 63;
  const int rl = l & 15, rq = l >> 4;
  const int wg = blockIdx.x;     // batch rows wg*16..
  const int colb = w*64;

  // persistent fp8 B fragments: [k-chunk][n-tile], 2 VGPRs each
  long Bfr[16][4];
  #pragma unroll
  for(int c=0;c<16;c++)
    #pragma unroll
    for(int tl=0;tl<4;tl++)
      Bfr[c][tl] = *(const long*)(W8 + (long)(colb + tl*16 + rl)*512 + c*32 + rq*8);

  float s_old[16];
  #pragma unroll
  for(int i=0;i<16;i++) s_old[i] = 0.f;

  // gate inputs for t=0: lane owns (m=rq*4+r, col=colb+tl*16+rl)
  unsigned int zv[16];
  #pragma unroll
  for(int tl=0;tl<4;tl++)
    #pragma unroll
    for(int r=0;r<4;r++)
      zv[tl*4+r] = ZV[(long)(wg*16 + rq*4 + r)*512 + colb + tl*16 + rl];

  for(int t = 0; t < S_DIM; t++){
    __syncthreads();   // prev-step LDS writes visible; prev reads done

    floatx4 acc[4];
    #pragma unroll
    for(int tl=0;tl<4;tl++) acc[tl] = (floatx4)0.f;

    if (t > 0){
      const unsigned char* sb = &stt[(t-1)&1][0][0];
      #pragma unroll
      for(int c=0;c<16;c++){
        long a = *(const long*)(sb + rl*520 + c*32 + rq*8);
        #pragma unroll
        for(int tl=0;tl<4;tl++)
          acc[tl] = __builtin_amdgcn_mfma_f32_16x16x32_fp8_fp8(a, Bfr[c][tl], acc[tl], 0, 0, 0);
      }
    }

    // prefetch next step's gate inputs (in flight across gate + barrier)
    unsigned int zvn[16];
    if (t+1 < S_DIM){
      #pragma unroll
      for(int tl=0;tl<4;tl++)
        #pragma unroll
        for(int r=0;r<4;r++)
          zvn[tl*4+r] = ZV[((long)(t+1)*64 + wg*16 + rq*4 + r)*512 + colb + tl*16 + rl];
    }

    // gate + state update
    unsigned short* cw = CONTB + ((long)t*64 + wg*16)*512;
    unsigned char* sw = &stt[t&1][0][0];
    #pragma unroll
    for(int tl=0;tl<4;tl++)
      #pragma unroll
      for(int r=0;r<4;r++){
        int m = rq*4 + r;
        int col = colb + tl*16 + rl;
        unsigned int p = zv[tl*4+r];
        float z = bf2f((unsigned short)(p & 0xffffu)) + acc[tl][r];
        float g = 1.f/(1.f + __expf(-z));
        float v = bf2f((unsigned short)(p >> 16));
        float s = s_old[tl*4+r]*g + v*(1.f - g);
        s_old[tl*4+r] = s;
        cw[(long)m*512 + col] = f2bf(s);
        __hip_fp8_e4m3 q(s);
        sw[m*520 + col] = q.__x;
      }

    #pragma unroll
    for(int i=0;i<16;i++) zv[i] = zvn[i];
  }
}

// ---------------- layernorm (bf16 in) + bf16 cast; 1 row per wave ----------------
__global__ __launch_bounds__(256) void ln_kernel(const unsigned short* __restrict__ contb,
    const float* __restrict__ lg, const float* __restrict__ lb,
    unsigned short* __restrict__ xln)
{
  const int wid = threadIdx.x >> 6, l = threadIdx.x & 63;
  const long row = (long)blockIdx.x*4 + wid;
  short8 xv = *(const short8*)(contb + row*F_DIM + l*8);
  float v[8];
  #pragma unroll
  for(int i=0;i<8;i++) v[i] = bf2f((unsigned short)xv[i]);
  float s = 0.f;
  #pragma unroll
  for(int i=0;i<8;i++) s += v[i];
  s = wsum(s);
  float mu = s * (1.f/512.f);
  float q = 0.f;
  #pragma unroll
  for(int i=0;i<8;i++){ float d = v[i]-mu; q += d*d; }
  q = wsum(q);
  float rs = rsqrtf(q*(1.f/512.f) + 1e-5f);
  short8 o;
  #pragma unroll
  for(int i=0;i<8;i++)
    o[i] = (short)f2bf((v[i]-mu)*rs*lg[l*8+i] + lb[l*8+i]);
  *(short8*)(xln + row*F_DIM + l*8) = o;
}

// ---------------- MFMA GEMM: C[M,N] = A[M,K] * B[N,K]^T (both row-major bf16) ----
// MODE 0: +bias, relu, store bf16.  MODE 1: +bias, store bf16.
// MODE 2: scale by 1/sqrt(F), per-row online-softmax partials per 128-col tile.
template<int MODE>
__global__ __launch_bounds__(256) void gemm_bt(
    const unsigned short* __restrict__ A,
    const unsigned short* __restrict__ Bm,
    const float* __restrict__ bias,
    unsigned short* __restrict__ C,
    float2* __restrict__ part,
    int M, int N, int K, int tiles_m, int tiles_n)
{
  __shared__ short As[128*64];
  __shared__ short Bs[128*64];
  __shared__ float sm[2][64][2][2];

  const int bid = blockIdx.x;
  const int mt = bid % tiles_m;
  const int nt = bid / tiles_m;
  const long m0 = (long)mt * 128;
  const long n0 = (long)nt * 128;
  const int tid = threadIdx.x;
  const int l = tid & 63;
  const int wid = tid >> 6;
  const int wr = wid >> 1, wc = wid & 1;
  const int rl = l & 15, rq = l >> 4;

  const short* Ag = (const short*)A + m0 * K;
  const short* Bg = (const short*)Bm + n0 * K;
  const int grow = tid >> 3;   // 0..31
  const int kp = tid & 7;      // 0..7

  floatx4 acc[4][4];
  #pragma unroll
  for(int i=0;i<4;i++)
    #pragma unroll
    for(int j=0;j<4;j++) acc[i][j] = (floatx4)0.f;

  for(int k0 = 0; k0 < K; k0 += 64){
    __syncthreads();
    #pragma unroll
    for(int ro = 0; ro < 128; ro += 32){
      load_lds16(Ag + (long)(ro + grow)*K + k0 + kp*8, (void*)(As + (ro+grow)*64 + kp*8));
      load_lds16(Bg + (long)(ro + grow)*K + k0 + kp*8, (void*)(Bs + (ro+grow)*64 + kp*8));
    }
    __syncthreads();
    #pragma unroll
    for(int kb = 0; kb < 64; kb += 32){
      short8 af[4], bfr[4];
      #pragma unroll
      for(int i=0;i<4;i++) af[i]  = *(const short8*)(As + (wr*64 + i*16 + rl)*64 + kb + rq*8);
      #pragma unroll
      for(int j=0;j<4;j++) bfr[j] = *(const short8*)(Bs + (wc*64 + j*16 + rl)*64 + kb + rq*8);
      #pragma unroll
      for(int i=0;i<4;i++)
        #pragma unroll
        for(int j=0;j<4;j++)
          acc[i][j] = __builtin_amdgcn_mfma_f32_16x16x32_bf16(af[i], bfr[j], acc[i][j], 0, 0, 0);
    }
  }

  const long mb = m0 + wr*64;
  const long nb = n0 + wc*64;
  if (MODE == 0 || MODE == 1){
    #pragma unroll
    for(int j=0;j<4;j++){
      float bj = bias[nb + j*16 + rl];
      #pragma unroll
      for(int i=0;i<4;i++){
        #pragma unroll
        for(int r=0;r<4;r++){
          float v = acc[i][j][r] + bj;
          if (MODE == 0) v = fmaxf(v, 0.f);
          C[(mb + i*16 + rq*4 + r)*N + nb + j*16 + rl] = f2bf(v);
        }
      }
    }
  } else {
    #pragma unroll
    for(int i=0;i<4;i++){
      #pragma unroll
      for(int r=0;r<4;r++){
        float mx = -3.4e38f;
        #pragma unroll
        for(int j=0;j<4;j++) mx = fmaxf(mx, acc[i][j][r]);
        #pragma unroll
        for(int d=1; d<16; d<<=1) mx = fmaxf(mx, __shfl_xor(mx, d));
        float ms = mx * SCALE;
        float sv = 0.f;
        #pragma unroll
        for(int j=0;j<4;j++) sv += expf(acc[i][j][r]*SCALE - ms);
        #pragma unroll
        for(int d=1; d<16; d<<=1) sv += __shfl_xor(sv, d);
        if (rl == 0){
          int rowl = i*16 + rq*4 + r;
          sm[wr][rowl][wc][0] = ms;
          sm[wr][rowl][wc][1] = sv;
        }
      }
    }
    __syncthreads();
    if (tid < 128){
      int wr2 = tid >> 6, rowl = tid & 63;
      float ma = sm[wr2][rowl][0][0], sa = sm[wr2][rowl][0][1];
      float mb2= sm[wr2][rowl][1][0], sb = sm[wr2][rowl][1][1];
      float Mn = fmaxf(ma, mb2);
      float Ln = sa*expf(ma - Mn) + sb*expf(mb2 - Mn);
      float2 o; o.x = Mn; o.y = Ln;
      part[(m0 + wr2*64 + rowl)*tiles_n + nt] = o;
    }
  }
}

// ---------------- target logit ----------------
__global__ __launch_bounds__(256) void tlogit_kernel(const unsigned short* __restrict__ outb,
    const unsigned short* __restrict__ embb, const int* __restrict__ tgt,
    float* __restrict__ TL)
{
  long gw = (long)blockIdx.x*4 + (threadIdx.x >> 6);
  int l = threadIdx.x & 63;
  int t = (int)(gw >> 6), b = (int)(gw & 63);
  int tg = tgt[b*S_DIM + t];
  const unsigned short* o = outb + gw*F_DIM;
  const unsigned short* e = embb + (long)tg*F_DIM;
  short8 ov = *(const short8*)(o + l*8);
  short8 ev = *(const short8*)(e + l*8);
  float s = 0.f;
  #pragma unroll
  for(int i=0;i<8;i++) s += bf2f((unsigned short)ov[i]) * bf2f((unsigned short)ev[i]);
  s = wsum(s);
  if (l == 0) TL[gw] = s * SCALE;
}

// ---------------- merge partials -> nll ----------------
__global__ __launch_bounds__(256) void lse_kernel(const float2* __restrict__ part,
    const float* __restrict__ TL, float* __restrict__ nll)
{
  long row = (long)blockIdx.x*4 + (threadIdx.x >> 6);
  int l = threadIdx.x & 63;
  float M = -3.4e38f, L = 0.f;
  for(int c = l; c < NT_LOG; c += 64){
    float2 pv = part[row*NT_LOG + c];
    float Mn = fmaxf(M, pv.x);
    L = L*expf(M - Mn) + pv.y*expf(pv.x - Mn);
    M = Mn;
  }
  #pragma unroll
  for(int d=1; d<64; d<<=1){
    float Mo = __shfl_xor(M, d), Lo = __shfl_xor(L, d);
    float Mn = fmaxf(M, Mo);
    L = L*expf(M - Mn) + Lo*expf(Mo - Mn);
    M = Mn;
  }
  if (l == 0) nll[row] = (M + logf(L)) - TL[row];
}

// ---------------- final loss ----------------
__global__ __launch_bounds__(256) void loss_kernel(const float* __restrict__ nll,
    const int* __restrict__ tgt, float* __restrict__ out)
{
  int t = threadIdx.x;
  float s = 0.f; int cnt = 0;
  for(int b = 0; b < B_DIM; b++){
    int v = tgt[b*S_DIM + t];
    if (v != 0){ s += nll[(long)t*B_DIM + b]; cnt++; }
  }
  float li = s / fmaxf((float)cnt, 1.f);
  li = wsum(li);
  __shared__ float red[4];
  if ((t & 63) == 0) red[t >> 6] = li;
  __syncthreads();
  if (t == 0) out[0] = (red[0]+red[1]+red[2]+red[3]) * (1.f/256.f);
}

extern "C" void kernel_launch(void* const* d_in, const int* in_sizes, int n_in,
                              void* d_out, int out_size, void* d_ws, size_t ws_size,
                              hipStream_t stream)
{
  const int*   inp   = (const int*)d_in[0];
  const int*   tgt   = (const int*)d_in[1];
  const float* see   = (const float*)d_in[2];
  const float* bias  = (const float*)d_in[3];
  const float* W_in  = (const float*)d_in[4];
  const float* b_in  = (const float*)d_in[5];
  const float* W_out = (const float*)d_in[6];
  const float* b_out = (const float*)d_in[7];
  const float* ln_g  = (const float*)d_in[8];
  const float* ln_b  = (const float*)d_in[9];
  const float* emb   = (const float*)d_in[10];

  char* p = (char*)d_ws;
  unsigned short* CONTB= (unsigned short*)p; p += (size_t)ROWS*F_DIM*2;   // 16.8 MB
  unsigned short* XLN  = (unsigned short*)p; p += (size_t)ROWS*F_DIM*2;   // 16.8 MB
  unsigned short* Hb   = (unsigned short*)p; p += (size_t)ROWS*H_DIM*2;   // 67.1 MB
  unsigned short* OUTb = (unsigned short*)p; p += (size_t)ROWS*F_DIM*2;   // 16.8 MB
  unsigned short* EMBb = (unsigned short*)p; p += (size_t)V_DIM*F_DIM*2;  // 32.8 MB
  unsigned short* WINb = (unsigned short*)p; p += (size_t)H_DIM*F_DIM*2;  //  2.1 MB
  unsigned short* WOUTb= (unsigned short*)p; p += (size_t)F_DIM*H_DIM*2;  //  2.1 MB
  float2* PART         = (float2*)p;         p += (size_t)ROWS*NT_LOG*8;  // 32.8 MB
  float* TL            = (float*)p;          p += (size_t)ROWS*4;
  float* NLL           = (float*)p;          p += (size_t)ROWS*4;
  unsigned short* VECSb= (unsigned short*)p; p += (size_t)ROWS*F_DIM*2;   // 16.8 MB
  unsigned short* Zb16 = (unsigned short*)p; p += (size_t)ROWS*F_DIM*2;   // 16.8 MB
  unsigned int* ZV     = (unsigned int*)p;   p += (size_t)ROWS*F_DIM*4;   // 33.6 MB
  unsigned short* SEETT= (unsigned short*)p; p += (size_t)F_DIM*F_DIM*2;  //  0.5 MB
  unsigned char* SEEB8 = (unsigned char*)p;  p += (size_t)F_DIM*F_DIM;    //  0.26 MB

  // independent prep
  cast_emb<<<4096, 256, 0, stream>>>(emb, EMBb);
  cast_w<<<2048, 256, 0, stream>>>(W_in,  WINb,  H_DIM*F_DIM);
  cast_w<<<2048, 256, 0, stream>>>(W_out, WOUTb, F_DIM*H_DIM);
  prep_see<<<512, 256, 0, stream>>>(see, SEETT, SEEB8);
  gather_vecs<<<ROWS/4, 256, 0, stream>>>(emb, inp, VECSb);

  // Z = vecs @ see_top + bias  (bf16 out), then pack with VECS
  gemm_bt<1><<<128*4, 256, 0, stream>>>(VECSb, SEETT, bias, Zb16, nullptr,
                                        ROWS, F_DIM, F_DIM, 128, 4);
  pack_zv<<<4096, 256, 0, stream>>>(Zb16, VECSb, ZV);

  // batch-parallel recurrence: 4 WGs, fp8-resident weights, no inter-block sync
  recurrence_batch<<<4, 512, 0, stream>>>(ZV, SEEB8, CONTB);

  // downstream
  ln_kernel<<<ROWS/4, 256, 0, stream>>>(CONTB, ln_g, ln_b, XLN);
  gemm_bt<0><<<128*16, 256, 0, stream>>>(XLN,  WINb,  b_in,  Hb,   nullptr, ROWS, H_DIM, F_DIM, 128, 16);
  gemm_bt<1><<<128*4,  256, 0, stream>>>(Hb,   WOUTb, b_out, OUTb, nullptr, ROWS, F_DIM, H_DIM, 128, 4);
  tlogit_kernel<<<ROWS/4, 256, 0, stream>>>(OUTb, EMBb, tgt, TL);
  gemm_bt<2><<<128*NT_LOG, 256, 0, stream>>>(OUTb, EMBb, nullptr, nullptr, PART, ROWS, V_DIM, F_DIM, 128, NT_LOG);
  lse_kernel<<<ROWS/4, 256, 0, stream>>>(PART, TL, NLL);
  loss_kernel<<<1, 256, 0, stream>>>(NLL, tgt, (float*)d_out);
}

// Round 6
// 1994.074 us; speedup vs baseline: 7.0001x; 1.1379x over previous
//
#include <hip/hip_runtime.h>
#include <hip/hip_fp8.h>

#define F_DIM 512
#define H_DIM 2048
#define V_DIM 32000
#define B_DIM 64
#define S_DIM 256
#define ROWS (S_DIM*B_DIM)          // 16384
#define NT_LOG 250                  // 32000/128
#define SCALE 0.04419417382415922f  // 1/sqrt(512)

typedef __attribute__((ext_vector_type(8))) short  short8;
typedef __attribute__((ext_vector_type(4))) float  floatx4;

static __device__ inline unsigned short f2bf(float x){
  unsigned int u = __float_as_uint(x);
  u += 0x7fffu + ((u >> 16) & 1u);           // RNE
  return (unsigned short)(u >> 16);
}
static __device__ inline float bf2f(unsigned short u){
  return __uint_as_float(((unsigned int)u) << 16);
}
static __device__ inline float wsum(float v){
  #pragma unroll
  for(int m = 32; m > 0; m >>= 1) v += __shfl_xor(v, m);
  return v;
}
static __device__ inline void load_lds16(const void* g, void* l){
  __builtin_amdgcn_global_load_lds((const __attribute__((address_space(1))) void*)g,
                                   (__attribute__((address_space(3))) void*)l, 16, 0, 0);
}

// ---------------- casts ----------------
__global__ __launch_bounds__(256) void cast_w(const float* __restrict__ src,
                                              unsigned short* __restrict__ dst, int n){
  int i = blockIdx.x*256 + threadIdx.x;
  int stride = gridDim.x*256;
  for(; i < n; i += stride) dst[i] = f2bf(src[i]);
}
__global__ __launch_bounds__(256) void cast_emb(const float* __restrict__ src,
                                                unsigned short* __restrict__ dst){
  int i = blockIdx.x*256 + threadIdx.x;
  int stride = gridDim.x*256;
  for(; i < V_DIM*F_DIM; i += stride){
    float v = (i < F_DIM) ? 0.f : src[i];    // PAD row (0) zeroed
    dst[i] = f2bf(v);
  }
}

// ---------------- prep: see_top^T bf16 (for Z gemm) + see_bot^T fp8 ----------
__global__ __launch_bounds__(256) void prep_see(const float* __restrict__ see,
    unsigned short* __restrict__ TT, unsigned char* __restrict__ B8){
  int n = blockIdx.x;
  for(int k = threadIdx.x; k < 512; k += 256){
    TT[n*512 + k] = f2bf(see[(long)k*512 + n]);
    __hip_fp8_e4m3 q(see[(long)(512+k)*512 + n]);
    B8[n*512 + k] = q.__x;
  }
}

// ---------------- gather embedding rows per (t,b), bf16; row = t*64+b -------
__global__ __launch_bounds__(256) void gather_vecs(const float* __restrict__ emb,
    const int* __restrict__ inp, unsigned short* __restrict__ V){
  long row = (long)blockIdx.x*4 + (threadIdx.x >> 6);
  int l = threadIdx.x & 63;
  int t = (int)(row >> 6), b = (int)(row & 63);
  int idx = inp[b*S_DIM + t];
  short8 o;
  if (idx == 0){
    #pragma unroll
    for(int i=0;i<8;i++) o[i] = 0;
  } else {
    const float* e = emb + (long)idx*F_DIM + l*8;
    float4 a = *(const float4*)e;
    float4 bq = *(const float4*)(e + 4);
    o[0]=(short)f2bf(a.x); o[1]=(short)f2bf(a.y); o[2]=(short)f2bf(a.z); o[3]=(short)f2bf(a.w);
    o[4]=(short)f2bf(bq.x);o[5]=(short)f2bf(bq.y);o[6]=(short)f2bf(bq.z);o[7]=(short)f2bf(bq.w);
  }
  *(short8*)(V + row*F_DIM + l*8) = o;
}

// ---------------- pack gate inputs: ZV = (vec_bf16 << 16) | z_bf16 ----------
__global__ __launch_bounds__(256) void pack_zv(const unsigned short* __restrict__ Zb,
    const unsigned short* __restrict__ V, unsigned int* __restrict__ ZV){
  int i = blockIdx.x*256 + threadIdx.x;
  int stride = gridDim.x*256;
  for(; i < ROWS*F_DIM; i += stride)
    ZV[i] = ((unsigned)V[i] << 16) | (unsigned)Zb[i];
}

// ---------------- batch-parallel recurrence, fp8-resident weights ----------
__global__ __launch_bounds__(512, 1) void recurrence_batch(
    const unsigned int* __restrict__ ZV,       // [16384,512] (vec<<16)|z  bf16 pair
    const unsigned char* __restrict__ W8,      // seeBotT fp8 [n=512][k=512]
    unsigned short* __restrict__ CONTB)        // [256][64][512] bf16 state history
{
  __shared__ unsigned char stt[2][16][520];    // 520 = 8B-aligned pad

  const int tid = threadIdx.x;
  const int w  = tid >> 6;       // wave 0..7 -> cols w*64..
  const int l  = tid & 63;
  const int rl = l & 15, rq = l >> 4;
  const int wg = blockIdx.x;     // batch rows wg*16..
  const int colb = w*64;

  // persistent fp8 B fragments: [k-chunk][n-tile], 2 VGPRs each
  long Bfr[16][4];
  #pragma unroll
  for(int c=0;c<16;c++)
    #pragma unroll
    for(int tl=0;tl<4;tl++)
      Bfr[c][tl] = *(const long*)(W8 + (long)(colb + tl*16 + rl)*512 + c*32 + rq*8);

  float s_old[16];
  #pragma unroll
  for(int i=0;i<16;i++) s_old[i] = 0.f;

  unsigned int zv[16];
  #pragma unroll
  for(int tl=0;tl<4;tl++)
    #pragma unroll
    for(int r=0;r<4;r++)
      zv[tl*4+r] = ZV[(long)(wg*16 + rq*4 + r)*512 + colb + tl*16 + rl];

  for(int t = 0; t < S_DIM; t++){
    __syncthreads();   // prev-step LDS writes visible; prev reads done

    floatx4 acc[4];
    #pragma unroll
    for(int tl=0;tl<4;tl++) acc[tl] = (floatx4)0.f;

    if (t > 0){
      const unsigned char* sb = &stt[(t-1)&1][0][0];
      #pragma unroll
      for(int c=0;c<16;c++){
        long a = *(const long*)(sb + rl*520 + c*32 + rq*8);
        #pragma unroll
        for(int tl=0;tl<4;tl++)
          acc[tl] = __builtin_amdgcn_mfma_f32_16x16x32_fp8_fp8(a, Bfr[c][tl], acc[tl], 0, 0, 0);
      }
    }

    unsigned int zvn[16];
    if (t+1 < S_DIM){
      #pragma unroll
      for(int tl=0;tl<4;tl++)
        #pragma unroll
        for(int r=0;r<4;r++)
          zvn[tl*4+r] = ZV[((long)(t+1)*64 + wg*16 + rq*4 + r)*512 + colb + tl*16 + rl];
    }

    unsigned short* cw = CONTB + ((long)t*64 + wg*16)*512;
    unsigned char* sw = &stt[t&1][0][0];
    #pragma unroll
    for(int tl=0;tl<4;tl++)
      #pragma unroll
      for(int r=0;r<4;r++){
        int m = rq*4 + r;
        int col = colb + tl*16 + rl;
        unsigned int p = zv[tl*4+r];
        float z = bf2f((unsigned short)(p & 0xffffu)) + acc[tl][r];
        float g = 1.f/(1.f + __expf(-z));
        float v = bf2f((unsigned short)(p >> 16));
        float s = s_old[tl*4+r]*g + v*(1.f - g);
        s_old[tl*4+r] = s;
        cw[(long)m*512 + col] = f2bf(s);
        __hip_fp8_e4m3 q(s);
        sw[m*520 + col] = q.__x;
      }

    #pragma unroll
    for(int i=0;i<16;i++) zv[i] = zvn[i];
  }
}

// ---------------- layernorm (bf16 in) + bf16 cast; 1 row per wave ----------------
__global__ __launch_bounds__(256) void ln_kernel(const unsigned short* __restrict__ contb,
    const float* __restrict__ lg, const float* __restrict__ lb,
    unsigned short* __restrict__ xln)
{
  const int wid = threadIdx.x >> 6, l = threadIdx.x & 63;
  const long row = (long)blockIdx.x*4 + wid;
  short8 xv = *(const short8*)(contb + row*F_DIM + l*8);
  float v[8];
  #pragma unroll
  for(int i=0;i<8;i++) v[i] = bf2f((unsigned short)xv[i]);
  float s = 0.f;
  #pragma unroll
  for(int i=0;i<8;i++) s += v[i];
  s = wsum(s);
  float mu = s * (1.f/512.f);
  float q = 0.f;
  #pragma unroll
  for(int i=0;i<8;i++){ float d = v[i]-mu; q += d*d; }
  q = wsum(q);
  float rs = rsqrtf(q*(1.f/512.f) + 1e-5f);
  short8 o;
  #pragma unroll
  for(int i=0;i<8;i++)
    o[i] = (short)f2bf((v[i]-mu)*rs*lg[l*8+i] + lb[l*8+i]);
  *(short8*)(xln + row*F_DIM + l*8) = o;
}

// ---------------- MFMA GEMM: C[M,N] = A[M,K] * B[N,K]^T (both row-major bf16) ----
// LDS tiles are XOR-swizzled: element (row, 16B-chunk c) lives at LDS chunk
// c^(row&7). Kills the 16-way bank conflict of the unswizzled layout (row
// stride = exactly 32 banks): fragment reads now spread uniformly, 8/bank
// per wave64 = minimum. Staging permutes the GLOBAL source chunk instead of
// the LDS dest (global_load_lds forces LDS dest = base + lane*16).
// MODE 0: +bias, relu, store bf16.  MODE 1: +bias, store bf16.
// MODE 2: scale by 1/sqrt(F), per-row online-softmax partials per 128-col tile.
template<int MODE>
__global__ __launch_bounds__(256) void gemm_bt(
    const unsigned short* __restrict__ A,
    const unsigned short* __restrict__ Bm,
    const float* __restrict__ bias,
    unsigned short* __restrict__ C,
    float2* __restrict__ part,
    int M, int N, int K, int tiles_m, int tiles_n)
{
  __shared__ short As[128*64];
  __shared__ short Bs[128*64];
  __shared__ float sm[2][64][2][2];

  const int bid = blockIdx.x;
  const int mt = bid % tiles_m;
  const int nt = bid / tiles_m;
  const long m0 = (long)mt * 128;
  const long n0 = (long)nt * 128;
  const int tid = threadIdx.x;
  const int l = tid & 63;
  const int wid = tid >> 6;
  const int wr = wid >> 1, wc = wid & 1;
  const int rl = l & 15, rq = l >> 4;

  const short* Ag = (const short*)A + m0 * K;
  const short* Bg = (const short*)Bm + n0 * K;
  const int grow = tid >> 3;   // 0..31
  const int kp = tid & 7;      // 0..7
  const int ksw = (kp ^ (grow & 7)) * 8;   // swizzled global chunk offset (shorts)

  floatx4 acc[4][4];
  #pragma unroll
  for(int i=0;i<4;i++)
    #pragma unroll
    for(int j=0;j<4;j++) acc[i][j] = (floatx4)0.f;

  for(int k0 = 0; k0 < K; k0 += 64){
    __syncthreads();
    #pragma unroll
    for(int ro = 0; ro < 128; ro += 32){
      load_lds16(Ag + (long)(ro + grow)*K + k0 + ksw, (void*)(As + (ro+grow)*64 + kp*8));
      load_lds16(Bg + (long)(ro + grow)*K + k0 + ksw, (void*)(Bs + (ro+grow)*64 + kp*8));
    }
    __syncthreads();
    #pragma unroll
    for(int kb = 0; kb < 64; kb += 32){
      const int cb = kb >> 3;              // base chunk: 0 or 4
      const int cl = ((cb + rq) ^ (rl & 7)) * 8;   // swizzled LDS chunk (shorts)
      short8 af[4], bfr[4];
      #pragma unroll
      for(int i=0;i<4;i++) af[i]  = *(const short8*)(As + (wr*64 + i*16 + rl)*64 + cl);
      #pragma unroll
      for(int j=0;j<4;j++) bfr[j] = *(const short8*)(Bs + (wc*64 + j*16 + rl)*64 + cl);
      #pragma unroll
      for(int i=0;i<4;i++)
        #pragma unroll
        for(int j=0;j<4;j++)
          acc[i][j] = __builtin_amdgcn_mfma_f32_16x16x32_bf16(af[i], bfr[j], acc[i][j], 0, 0, 0);
    }
  }

  const long mb = m0 + wr*64;
  const long nb = n0 + wc*64;
  if (MODE == 0 || MODE == 1){
    #pragma unroll
    for(int j=0;j<4;j++){
      float bj = bias[nb + j*16 + rl];
      #pragma unroll
      for(int i=0;i<4;i++){
        #pragma unroll
        for(int r=0;r<4;r++){
          float v = acc[i][j][r] + bj;
          if (MODE == 0) v = fmaxf(v, 0.f);
          C[(mb + i*16 + rq*4 + r)*N + nb + j*16 + rl] = f2bf(v);
        }
      }
    }
  } else {
    #pragma unroll
    for(int i=0;i<4;i++){
      #pragma unroll
      for(int r=0;r<4;r++){
        float mx = -3.4e38f;
        #pragma unroll
        for(int j=0;j<4;j++) mx = fmaxf(mx, acc[i][j][r]);
        #pragma unroll
        for(int d=1; d<16; d<<=1) mx = fmaxf(mx, __shfl_xor(mx, d));
        float ms = mx * SCALE;
        float sv = 0.f;
        #pragma unroll
        for(int j=0;j<4;j++) sv += expf(acc[i][j][r]*SCALE - ms);
        #pragma unroll
        for(int d=1; d<16; d<<=1) sv += __shfl_xor(sv, d);
        if (rl == 0){
          int rowl = i*16 + rq*4 + r;
          sm[wr][rowl][wc][0] = ms;
          sm[wr][rowl][wc][1] = sv;
        }
      }
    }
    __syncthreads();
    if (tid < 128){
      int wr2 = tid >> 6, rowl = tid & 63;
      float ma = sm[wr2][rowl][0][0], sa = sm[wr2][rowl][0][1];
      float mb2= sm[wr2][rowl][1][0], sb = sm[wr2][rowl][1][1];
      float Mn = fmaxf(ma, mb2);
      float Ln = sa*expf(ma - Mn) + sb*expf(mb2 - Mn);
      float2 o; o.x = Mn; o.y = Ln;
      part[(m0 + wr2*64 + rowl)*tiles_n + nt] = o;
    }
  }
}

// ---------------- target logit ----------------
__global__ __launch_bounds__(256) void tlogit_kernel(const unsigned short* __restrict__ outb,
    const unsigned short* __restrict__ embb, const int* __restrict__ tgt,
    float* __restrict__ TL)
{
  long gw = (long)blockIdx.x*4 + (threadIdx.x >> 6);
  int l = threadIdx.x & 63;
  int t = (int)(gw >> 6), b = (int)(gw & 63);
  int tg = tgt[b*S_DIM + t];
  const unsigned short* o = outb + gw*F_DIM;
  const unsigned short* e = embb + (long)tg*F_DIM;
  short8 ov = *(const short8*)(o + l*8);
  short8 ev = *(const short8*)(e + l*8);
  float s = 0.f;
  #pragma unroll
  for(int i=0;i<8;i++) s += bf2f((unsigned short)ov[i]) * bf2f((unsigned short)ev[i]);
  s = wsum(s);
  if (l == 0) TL[gw] = s * SCALE;
}

// ---------------- merge partials -> nll ----------------
__global__ __launch_bounds__(256) void lse_kernel(const float2* __restrict__ part,
    const float* __restrict__ TL, float* __restrict__ nll)
{
  long row = (long)blockIdx.x*4 + (threadIdx.x >> 6);
  int l = threadIdx.x & 63;
  float M = -3.4e38f, L = 0.f;
  for(int c = l; c < NT_LOG; c += 64){
    float2 pv = part[row*NT_LOG + c];
    float Mn = fmaxf(M, pv.x);
    L = L*expf(M - Mn) + pv.y*expf(pv.x - Mn);
    M = Mn;
  }
  #pragma unroll
  for(int d=1; d<64; d<<=1){
    float Mo = __shfl_xor(M, d), Lo = __shfl_xor(L, d);
    float Mn = fmaxf(M, Mo);
    L = L*expf(M - Mn) + Lo*expf(Mo - Mn);
    M = Mn;
  }
  if (l == 0) nll[row] = (M + logf(L)) - TL[row];
}

// ---------------- final loss ----------------
__global__ __launch_bounds__(256) void loss_kernel(const float* __restrict__ nll,
    const int* __restrict__ tgt, float* __restrict__ out)
{
  int t = threadIdx.x;
  float s = 0.f; int cnt = 0;
  for(int b = 0; b < B_DIM; b++){
    int v = tgt[b*S_DIM + t];
    if (v != 0){ s += nll[(long)t*B_DIM + b]; cnt++; }
  }
  float li = s / fmaxf((float)cnt, 1.f);
  li = wsum(li);
  __shared__ float red[4];
  if ((t & 63) == 0) red[t >> 6] = li;
  __syncthreads();
  if (t == 0) out[0] = (red[0]+red[1]+red[2]+red[3]) * (1.f/256.f);
}

extern "C" void kernel_launch(void* const* d_in, const int* in_sizes, int n_in,
                              void* d_out, int out_size, void* d_ws, size_t ws_size,
                              hipStream_t stream)
{
  const int*   inp   = (const int*)d_in[0];
  const int*   tgt   = (const int*)d_in[1];
  const float* see   = (const float*)d_in[2];
  const float* bias  = (const float*)d_in[3];
  const float* W_in  = (const float*)d_in[4];
  const float* b_in  = (const float*)d_in[5];
  const float* W_out = (const float*)d_in[6];
  const float* b_out = (const float*)d_in[7];
  const float* ln_g  = (const float*)d_in[8];
  const float* ln_b  = (const float*)d_in[9];
  const float* emb   = (const float*)d_in[10];

  char* p = (char*)d_ws;
  unsigned short* CONTB= (unsigned short*)p; p += (size_t)ROWS*F_DIM*2;   // 16.8 MB
  unsigned short* XLN  = (unsigned short*)p; p += (size_t)ROWS*F_DIM*2;   // 16.8 MB
  unsigned short* Hb   = (unsigned short*)p; p += (size_t)ROWS*H_DIM*2;   // 67.1 MB
  unsigned short* OUTb = (unsigned short*)p; p += (size_t)ROWS*F_DIM*2;   // 16.8 MB
  unsigned short* EMBb = (unsigned short*)p; p += (size_t)V_DIM*F_DIM*2;  // 32.8 MB
  unsigned short* WINb = (unsigned short*)p; p += (size_t)H_DIM*F_DIM*2;  //  2.1 MB
  unsigned short* WOUTb= (unsigned short*)p; p += (size_t)F_DIM*H_DIM*2;  //  2.1 MB
  float2* PART         = (float2*)p;         p += (size_t)ROWS*NT_LOG*8;  // 32.8 MB
  float* TL            = (float*)p;          p += (size_t)ROWS*4;
  float* NLL           = (float*)p;          p += (size_t)ROWS*4;
  unsigned short* VECSb= (unsigned short*)p; p += (size_t)ROWS*F_DIM*2;   // 16.8 MB
  unsigned short* Zb16 = (unsigned short*)p; p += (size_t)ROWS*F_DIM*2;   // 16.8 MB
  unsigned int* ZV     = (unsigned int*)p;   p += (size_t)ROWS*F_DIM*4;   // 33.6 MB
  unsigned short* SEETT= (unsigned short*)p; p += (size_t)F_DIM*F_DIM*2;  //  0.5 MB
  unsigned char* SEEB8 = (unsigned char*)p;  p += (size_t)F_DIM*F_DIM;    //  0.26 MB

  // independent prep
  cast_emb<<<4096, 256, 0, stream>>>(emb, EMBb);
  cast_w<<<2048, 256, 0, stream>>>(W_in,  WINb,  H_DIM*F_DIM);
  cast_w<<<2048, 256, 0, stream>>>(W_out, WOUTb, F_DIM*H_DIM);
  prep_see<<<512, 256, 0, stream>>>(see, SEETT, SEEB8);
  gather_vecs<<<ROWS/4, 256, 0, stream>>>(emb, inp, VECSb);

  // Z = vecs @ see_top + bias  (bf16 out), then pack with VECS
  gemm_bt<1><<<128*4, 256, 0, stream>>>(VECSb, SEETT, bias, Zb16, nullptr,
                                        ROWS, F_DIM, F_DIM, 128, 4);
  pack_zv<<<4096, 256, 0, stream>>>(Zb16, VECSb, ZV);

  // batch-parallel recurrence: 4 WGs, fp8-resident weights, no inter-block sync
  recurrence_batch<<<4, 512, 0, stream>>>(ZV, SEEB8, CONTB);

  // downstream
  ln_kernel<<<ROWS/4, 256, 0, stream>>>(CONTB, ln_g, ln_b, XLN);
  gemm_bt<0><<<128*16, 256, 0, stream>>>(XLN,  WINb,  b_in,  Hb,   nullptr, ROWS, H_DIM, F_DIM, 128, 16);
  gemm_bt<1><<<128*4,  256, 0, stream>>>(Hb,   WOUTb, b_out, OUTb, nullptr, ROWS, F_DIM, H_DIM, 128, 4);
  tlogit_kernel<<<ROWS/4, 256, 0, stream>>>(OUTb, EMBb, tgt, TL);
  gemm_bt<2><<<128*NT_LOG, 256, 0, stream>>>(OUTb, EMBb, nullptr, nullptr, PART, ROWS, V_DIM, F_DIM, 128, NT_LOG);
  lse_kernel<<<ROWS/4, 256, 0, stream>>>(PART, TL, NLL);
  loss_kernel<<<1, 256, 0, stream>>>(NLL, tgt, (float*)d_out);
}

// Round 8
// 1923.610 us; speedup vs baseline: 7.2565x; 1.0366x over previous
//
#include <hip/hip_runtime.h>
#include <hip/hip_fp8.h>

#define F_DIM 512
#define H_DIM 2048
#define V_DIM 32000
#define B_DIM 64
#define S_DIM 256
#define ROWS (S_DIM*B_DIM)          // 16384
#define NT_LOG 250                  // 32000/128
#define SCALE 0.04419417382415922f  // 1/sqrt(512)

typedef __attribute__((ext_vector_type(8))) short  short8;
typedef __attribute__((ext_vector_type(4))) float  floatx4;

static __device__ inline unsigned short f2bf(float x){
  unsigned int u = __float_as_uint(x);
  u += 0x7fffu + ((u >> 16) & 1u);           // RNE
  return (unsigned short)(u >> 16);
}
static __device__ inline float bf2f(unsigned short u){
  return __uint_as_float(((unsigned int)u) << 16);
}
static __device__ inline unsigned char f2fp8(float x){
  __hip_fp8_e4m3 q(x);
  return q.__x;
}
static __device__ inline float wsum(float v){
  #pragma unroll
  for(int m = 32; m > 0; m >>= 1) v += __shfl_xor(v, m);
  return v;
}
static __device__ inline void load_lds16(const void* g, void* l){
  __builtin_amdgcn_global_load_lds((const __attribute__((address_space(1))) void*)g,
                                   (__attribute__((address_space(3))) void*)l, 16, 0, 0);
}

// ---------------- casts ----------------
__global__ __launch_bounds__(256) void cast_w(const float* __restrict__ src,
                                              unsigned short* __restrict__ dst, int n){
  int i = blockIdx.x*256 + threadIdx.x;
  int stride = gridDim.x*256;
  for(; i < n; i += stride) dst[i] = f2bf(src[i]);
}
// emb -> bf16 (for tlogit) + fp8 (for logits GEMM), PAD row zeroed
__global__ __launch_bounds__(256) void cast_emb(const float* __restrict__ src,
    unsigned short* __restrict__ dst, unsigned char* __restrict__ d8){
  int i = blockIdx.x*256 + threadIdx.x;
  int stride = gridDim.x*256;
  for(; i < V_DIM*F_DIM; i += stride){
    float v = (i < F_DIM) ? 0.f : src[i];
    dst[i] = f2bf(v);
    d8[i] = f2fp8(v);
  }
}

// ---------------- prep: see_top^T bf16 (for Z gemm) + see_bot^T fp8 ----------
__global__ __launch_bounds__(256) void prep_see(const float* __restrict__ see,
    unsigned short* __restrict__ TT, unsigned char* __restrict__ B8){
  int n = blockIdx.x;
  for(int k = threadIdx.x; k < 512; k += 256){
    TT[n*512 + k] = f2bf(see[(long)k*512 + n]);
    B8[n*512 + k] = f2fp8(see[(long)(512+k)*512 + n]);
  }
}

// ---------------- gather embedding rows per (t,b), bf16; row = t*64+b -------
__global__ __launch_bounds__(256) void gather_vecs(const float* __restrict__ emb,
    const int* __restrict__ inp, unsigned short* __restrict__ V){
  long row = (long)blockIdx.x*4 + (threadIdx.x >> 6);
  int l = threadIdx.x & 63;
  int t = (int)(row >> 6), b = (int)(row & 63);
  int idx = inp[b*S_DIM + t];
  short8 o;
  if (idx == 0){
    #pragma unroll
    for(int i=0;i<8;i++) o[i] = 0;
  } else {
    const float* e = emb + (long)idx*F_DIM + l*8;
    float4 a = *(const float4*)e;
    float4 bq = *(const float4*)(e + 4);
    o[0]=(short)f2bf(a.x); o[1]=(short)f2bf(a.y); o[2]=(short)f2bf(a.z); o[3]=(short)f2bf(a.w);
    o[4]=(short)f2bf(bq.x);o[5]=(short)f2bf(bq.y);o[6]=(short)f2bf(bq.z);o[7]=(short)f2bf(bq.w);
  }
  *(short8*)(V + row*F_DIM + l*8) = o;
}

// ---------------- batch-parallel recurrence, fp8-resident weights ----------
__global__ __launch_bounds__(512, 1) void recurrence_batch(
    const unsigned int* __restrict__ ZV,       // [16384,512] (vec<<16)|z  bf16 pair
    const unsigned char* __restrict__ W8,      // seeBotT fp8 [n=512][k=512]
    unsigned short* __restrict__ CONTB)        // [256][64][512] bf16 state history
{
  __shared__ unsigned char stt[2][16][520];    // 520 = 8B-aligned pad

  const int tid = threadIdx.x;
  const int w  = tid >> 6;       // wave 0..7 -> cols w*64..
  const int l  = tid & 63;
  const int rl = l & 15, rq = l >> 4;
  const int wg = blockIdx.x;     // batch rows wg*16..
  const int colb = w*64;

  // persistent fp8 B fragments: [k-chunk][n-tile], 2 VGPRs each = 128 VGPRs
  long Bfr[16][4];
  #pragma unroll
  for(int c=0;c<16;c++)
    #pragma unroll
    for(int tl=0;tl<4;tl++)
      Bfr[c][tl] = *(const long*)(W8 + (long)(colb + tl*16 + rl)*512 + c*32 + rq*8);

  float s_old[16];
  #pragma unroll
  for(int i=0;i<16;i++) s_old[i] = 0.f;

  unsigned int zv[16];
  #pragma unroll
  for(int tl=0;tl<4;tl++)
    #pragma unroll
    for(int r=0;r<4;r++)
      zv[tl*4+r] = ZV[(long)(wg*16 + rq*4 + r)*512 + colb + tl*16 + rl];

  for(int t = 0; t < S_DIM; t++){
    __syncthreads();   // prev-step LDS writes visible; prev reads done

    floatx4 acc[4];
    #pragma unroll
    for(int tl=0;tl<4;tl++) acc[tl] = (floatx4)0.f;

    if (t > 0){
      const unsigned char* sb = &stt[(t-1)&1][0][0];
      #pragma unroll
      for(int c=0;c<16;c++){
        long a = *(const long*)(sb + rl*520 + c*32 + rq*8);
        #pragma unroll
        for(int tl=0;tl<4;tl++)
          acc[tl] = __builtin_amdgcn_mfma_f32_16x16x32_fp8_fp8(a, Bfr[c][tl], acc[tl], 0, 0, 0);
      }
    }

    unsigned int zvn[16];
    if (t+1 < S_DIM){
      #pragma unroll
      for(int tl=0;tl<4;tl++)
        #pragma unroll
        for(int r=0;r<4;r++)
          zvn[tl*4+r] = ZV[((long)(t+1)*64 + wg*16 + rq*4 + r)*512 + colb + tl*16 + rl];
    }

    unsigned short* cw = CONTB + ((long)t*64 + wg*16)*512;
    unsigned char* sw = &stt[t&1][0][0];
    #pragma unroll
    for(int tl=0;tl<4;tl++)
      #pragma unroll
      for(int r=0;r<4;r++){
        int m = rq*4 + r;
        int col = colb + tl*16 + rl;
        unsigned int p = zv[tl*4+r];
        float z = bf2f((unsigned short)(p & 0xffffu)) + acc[tl][r];
        float g = 1.f/(1.f + __expf(-z));
        float v = bf2f((unsigned short)(p >> 16));
        float s = s_old[tl*4+r]*g + v*(1.f - g);
        s_old[tl*4+r] = s;
        cw[(long)m*512 + col] = f2bf(s);
        sw[m*520 + col] = f2fp8(s);
      }

    #pragma unroll
    for(int i=0;i<16;i++) zv[i] = zvn[i];
  }
}

// ---------------- layernorm (bf16 in) + bf16 cast; 1 row per wave ----------------
__global__ __launch_bounds__(256) void ln_kernel(const unsigned short* __restrict__ contb,
    const float* __restrict__ lg, const float* __restrict__ lb,
    unsigned short* __restrict__ xln)
{
  const int wid = threadIdx.x >> 6, l = threadIdx.x & 63;
  const long row = (long)blockIdx.x*4 + wid;
  short8 xv = *(const short8*)(contb + row*F_DIM + l*8);
  float v[8];
  #pragma unroll
  for(int i=0;i<8;i++) v[i] = bf2f((unsigned short)xv[i]);
  float s = 0.f;
  #pragma unroll
  for(int i=0;i<8;i++) s += v[i];
  s = wsum(s);
  float mu = s * (1.f/512.f);
  float q = 0.f;
  #pragma unroll
  for(int i=0;i<8;i++){ float d = v[i]-mu; q += d*d; }
  q = wsum(q);
  float rs = rsqrtf(q*(1.f/512.f) + 1e-5f);
  short8 o;
  #pragma unroll
  for(int i=0;i<8;i++)
    o[i] = (short)f2bf((v[i]-mu)*rs*lg[l*8+i] + lb[l*8+i]);
  *(short8*)(xln + row*F_DIM + l*8) = o;
}

// ---------------- bf16 MFMA GEMM: C[M,N] = A[M,K] * B[N,K]^T ----------------
// XOR-swizzled LDS (r6: conflicts 1.97e8 -> 0).
// MODE 0: +bias, relu, store bf16.
// MODE 4: +bias, store bf16 AND fp8 (logits-GEMM input).
// MODE 5: +bias, store packed ZV word: (Vsrc<<16)|bf16(v)  (recurrence input).
template<int MODE>
__global__ __launch_bounds__(256) void gemm_bt(
    const unsigned short* __restrict__ A,
    const unsigned short* __restrict__ Bm,
    const float* __restrict__ bias,
    unsigned short* __restrict__ C,
    unsigned char* __restrict__ C8,
    const unsigned short* __restrict__ Vsrc,
    unsigned int* __restrict__ ZVout,
    int M, int N, int K, int tiles_m, int tiles_n)
{
  __shared__ short As[128*64];
  __shared__ short Bs[128*64];

  const int bid = blockIdx.x;
  const int mt = bid % tiles_m;
  const int nt = bid / tiles_m;
  const long m0 = (long)mt * 128;
  const long n0 = (long)nt * 128;
  const int tid = threadIdx.x;
  const int l = tid & 63;
  const int wid = tid >> 6;
  const int wr = wid >> 1, wc = wid & 1;
  const int rl = l & 15, rq = l >> 4;

  const short* Ag = (const short*)A + m0 * K;
  const short* Bg = (const short*)Bm + n0 * K;
  const int grow = tid >> 3;   // 0..31
  const int kp = tid & 7;      // 0..7
  const int ksw = (kp ^ (grow & 7)) * 8;   // swizzled global chunk offset (shorts)

  floatx4 acc[4][4];
  #pragma unroll
  for(int i=0;i<4;i++)
    #pragma unroll
    for(int j=0;j<4;j++) acc[i][j] = (floatx4)0.f;

  for(int k0 = 0; k0 < K; k0 += 64){
    __syncthreads();
    #pragma unroll
    for(int ro = 0; ro < 128; ro += 32){
      load_lds16(Ag + (long)(ro + grow)*K + k0 + ksw, (void*)(As + (ro+grow)*64 + kp*8));
      load_lds16(Bg + (long)(ro + grow)*K + k0 + ksw, (void*)(Bs + (ro+grow)*64 + kp*8));
    }
    __syncthreads();
    #pragma unroll
    for(int kb = 0; kb < 64; kb += 32){
      const int cb = kb >> 3;              // base chunk: 0 or 4
      const int cl = ((cb + rq) ^ (rl & 7)) * 8;   // swizzled LDS chunk (shorts)
      short8 af[4], bfr[4];
      #pragma unroll
      for(int i=0;i<4;i++) af[i]  = *(const short8*)(As + (wr*64 + i*16 + rl)*64 + cl);
      #pragma unroll
      for(int j=0;j<4;j++) bfr[j] = *(const short8*)(Bs + (wc*64 + j*16 + rl)*64 + cl);
      #pragma unroll
      for(int i=0;i<4;i++)
        #pragma unroll
        for(int j=0;j<4;j++)
          acc[i][j] = __builtin_amdgcn_mfma_f32_16x16x32_bf16(af[i], bfr[j], acc[i][j], 0, 0, 0);
    }
  }

  const long mb = m0 + wr*64;
  const long nb = n0 + wc*64;
  #pragma unroll
  for(int j=0;j<4;j++){
    float bj = bias[nb + j*16 + rl];
    #pragma unroll
    for(int i=0;i<4;i++){
      #pragma unroll
      for(int r=0;r<4;r++){
        float v = acc[i][j][r] + bj;
        if (MODE == 0) v = fmaxf(v, 0.f);
        long idx = (mb + i*16 + rq*4 + r)*N + nb + j*16 + rl;
        if (MODE == 5){
          ZVout[idx] = ((unsigned)Vsrc[idx] << 16) | (unsigned)f2bf(v);
        } else {
          C[idx] = f2bf(v);
          if (MODE == 4) C8[idx] = f2fp8(v);
        }
      }
    }
  }
}

// ---------------- fp8 logits GEMM + online-softmax partials ----------------
// C = (A8[M,512] . B8[N,512]^T) * SCALE, per-row (max,sumexp) per 128-col tile.
// fp8 halves LDS traffic (ds_read_b64), staging bytes, FETCH vs bf16 — the r6
// bf16 version was LDS/VALU-fed-starved (MfmaUtil 24%, VALUBusy 63%).
// LDS rows = 64 B; 16-B chunk swizzle c^(row&3) -> uniform 4 acc/bank (min).
__global__ __launch_bounds__(256) void gemm_f8_logits(
    const unsigned char* __restrict__ A8,
    const unsigned char* __restrict__ B8,
    float2* __restrict__ part,
    int M, int N, int K, int tiles_m, int tiles_n)
{
  __shared__ unsigned char As8[128*64];
  __shared__ unsigned char Bs8[128*64];
  __shared__ float sm[2][64][2][2];

  const int bid = blockIdx.x;
  const int mt = bid % tiles_m;
  const int nt = bid / tiles_m;
  const long m0 = (long)mt * 128;
  const long n0 = (long)nt * 128;
  const int tid = threadIdx.x;
  const int l = tid & 63;
  const int wid = tid >> 6;
  const int wr = wid >> 1, wc = wid & 1;
  const int rl = l & 15, rq = l >> 4;

  const unsigned char* Ag = A8 + m0 * K;
  const unsigned char* Bg = B8 + n0 * K;
  const int grow = tid >> 2;               // 0..63
  const int kp = tid & 3;                  // 0..3
  const int ksw = (kp ^ (grow & 3)) << 4;  // swizzled global chunk (bytes)

  floatx4 acc[4][4];
  #pragma unroll
  for(int i=0;i<4;i++)
    #pragma unroll
    for(int j=0;j<4;j++) acc[i][j] = (floatx4)0.f;

  for(int k0 = 0; k0 < K; k0 += 64){
    __syncthreads();
    #pragma unroll
    for(int ro = 0; ro < 128; ro += 64){
      load_lds16(Ag + (long)(ro + grow)*K + k0 + ksw, (void*)(As8 + (ro+grow)*64 + kp*16));
      load_lds16(Bg + (long)(ro + grow)*K + k0 + ksw, (void*)(Bs8 + (ro+grow)*64 + kp*16));
    }
    __syncthreads();
    #pragma unroll
    for(int kb = 0; kb < 64; kb += 32){
      const int c = (kb >> 4) + (rq >> 1);
      const int lo = (rq & 1) * 8;
      const int cl = ((c ^ (rl & 3)) << 4) + lo;   // swizzled LDS byte offset
      long af[4], bfr[4];
      #pragma unroll
      for(int i=0;i<4;i++) af[i]  = *(const long*)(As8 + (wr*64 + i*16 + rl)*64 + cl);
      #pragma unroll
      for(int j=0;j<4;j++) bfr[j] = *(const long*)(Bs8 + (wc*64 + j*16 + rl)*64 + cl);
      #pragma unroll
      for(int i=0;i<4;i++)
        #pragma unroll
        for(int j=0;j<4;j++)
          acc[i][j] = __builtin_amdgcn_mfma_f32_16x16x32_fp8_fp8(af[i], bfr[j], acc[i][j], 0, 0, 0);
    }
  }

  // online-softmax partials per 128-col tile
  #pragma unroll
  for(int i=0;i<4;i++){
    #pragma unroll
    for(int r=0;r<4;r++){
      float mx = -3.4e38f;
      #pragma unroll
      for(int j=0;j<4;j++) mx = fmaxf(mx, acc[i][j][r]);
      #pragma unroll
      for(int d=1; d<16; d<<=1) mx = fmaxf(mx, __shfl_xor(mx, d));
      float ms = mx * SCALE;
      float sv = 0.f;
      #pragma unroll
      for(int j=0;j<4;j++) sv += expf(acc[i][j][r]*SCALE - ms);
      #pragma unroll
      for(int d=1; d<16; d<<=1) sv += __shfl_xor(sv, d);
      if (rl == 0){
        int rowl = i*16 + rq*4 + r;
        sm[wr][rowl][wc][0] = ms;
        sm[wr][rowl][wc][1] = sv;
      }
    }
  }
  __syncthreads();
  if (tid < 128){
    int wr2 = tid >> 6, rowl = tid & 63;
    float ma = sm[wr2][rowl][0][0], sa = sm[wr2][rowl][0][1];
    float mb2= sm[wr2][rowl][1][0], sb = sm[wr2][rowl][1][1];
    float Mn = fmaxf(ma, mb2);
    float Ln = sa*expf(ma - Mn) + sb*expf(mb2 - Mn);
    float2 o; o.x = Mn; o.y = Ln;
    part[(m0 + wr2*64 + rowl)*tiles_n + nt] = o;
  }
}

// ---------------- target logit (bf16 inputs — more accurate than fp8 LSE side) --
__global__ __launch_bounds__(256) void tlogit_kernel(const unsigned short* __restrict__ outb,
    const unsigned short* __restrict__ embb, const int* __restrict__ tgt,
    float* __restrict__ TL)
{
  long gw = (long)blockIdx.x*4 + (threadIdx.x >> 6);
  int l = threadIdx.x & 63;
  int t = (int)(gw >> 6), b = (int)(gw & 63);
  int tg = tgt[b*S_DIM + t];
  const unsigned short* o = outb + gw*F_DIM;
  const unsigned short* e = embb + (long)tg*F_DIM;
  short8 ov = *(const short8*)(o + l*8);
  short8 ev = *(const short8*)(e + l*8);
  float s = 0.f;
  #pragma unroll
  for(int i=0;i<8;i++) s += bf2f((unsigned short)ov[i]) * bf2f((unsigned short)ev[i]);
  s = wsum(s);
  if (l == 0) TL[gw] = s * SCALE;
}

// ---------------- merge partials -> nll ----------------
__global__ __launch_bounds__(256) void lse_kernel(const float2* __restrict__ part,
    const float* __restrict__ TL, float* __restrict__ nll)
{
  long row = (long)blockIdx.x*4 + (threadIdx.x >> 6);
  int l = threadIdx.x & 63;
  float M = -3.4e38f, L = 0.f;
  for(int c = l; c < NT_LOG; c += 64){
    float2 pv = part[row*NT_LOG + c];
    float Mn = fmaxf(M, pv.x);
    L = L*expf(M - Mn) + pv.y*expf(pv.x - Mn);
    M = Mn;
  }
  #pragma unroll
  for(int d=1; d<64; d<<=1){
    float Mo = __shfl_xor(M, d), Lo = __shfl_xor(L, d);
    float Mn = fmaxf(M, Mo);
    L = L*expf(M - Mn) + Lo*expf(Mo - Mn);
    M = Mn;
  }
  if (l == 0) nll[row] = (M + logf(L)) - TL[row];
}

// ---------------- final loss ----------------
__global__ __launch_bounds__(256) void loss_kernel(const float* __restrict__ nll,
    const int* __restrict__ tgt, float* __restrict__ out)
{
  int t = threadIdx.x;
  float s = 0.f; int cnt = 0;
  for(int b = 0; b < B_DIM; b++){
    int v = tgt[b*S_DIM + t];
    if (v != 0){ s += nll[(long)t*B_DIM + b]; cnt++; }
  }
  float li = s / fmaxf((float)cnt, 1.f);
  li = wsum(li);
  __shared__ float red[4];
  if ((t & 63) == 0) red[t >> 6] = li;
  __syncthreads();
  if (t == 0) out[0] = (red[0]+red[1]+red[2]+red[3]) * (1.f/256.f);
}

extern "C" void kernel_launch(void* const* d_in, const int* in_sizes, int n_in,
                              void* d_out, int out_size, void* d_ws, size_t ws_size,
                              hipStream_t stream)
{
  const int*   inp   = (const int*)d_in[0];
  const int*   tgt   = (const int*)d_in[1];
  const float* see   = (const float*)d_in[2];
  const float* bias  = (const float*)d_in[3];
  const float* W_in  = (const float*)d_in[4];
  const float* b_in  = (const float*)d_in[5];
  const float* W_out = (const float*)d_in[6];
  const float* b_out = (const float*)d_in[7];
  const float* ln_g  = (const float*)d_in[8];
  const float* ln_b  = (const float*)d_in[9];
  const float* emb   = (const float*)d_in[10];

  // Workspace plan — peak ~205 MB (r7's 280 MB overflowed the ~256 MB pool).
  // Aliases are safe by stream order:
  //   XLN  aliases ZV     (ZV dead after recurrence; XLN born at ln)
  //   OUT8 aliases VECSb  (VECSb dead after Z-gemm; OUT8 born at FFN2)
  //   PART aliases Hb     (Hb dead after FFN2; PART born at logits gemm)
  char* p = (char*)d_ws;
  unsigned short* CONTB= (unsigned short*)p; p += (size_t)ROWS*F_DIM*2;   // 16.8 MB
  unsigned short* Hb   = (unsigned short*)p; p += (size_t)ROWS*H_DIM*2;   // 67.1 MB
  unsigned short* OUTb = (unsigned short*)p; p += (size_t)ROWS*F_DIM*2;   // 16.8 MB
  unsigned short* EMBb = (unsigned short*)p; p += (size_t)V_DIM*F_DIM*2;  // 32.8 MB
  unsigned char* EMB8  = (unsigned char*)p;  p += (size_t)V_DIM*F_DIM;    // 16.4 MB
  unsigned short* WINb = (unsigned short*)p; p += (size_t)H_DIM*F_DIM*2;  //  2.1 MB
  unsigned short* WOUTb= (unsigned short*)p; p += (size_t)F_DIM*H_DIM*2;  //  2.1 MB
  float* TL            = (float*)p;          p += (size_t)ROWS*4;
  float* NLL           = (float*)p;          p += (size_t)ROWS*4;
  unsigned short* VECSb= (unsigned short*)p; p += (size_t)ROWS*F_DIM*2;   // 16.8 MB
  unsigned int* ZV     = (unsigned int*)p;   p += (size_t)ROWS*F_DIM*4;   // 33.6 MB
  unsigned short* SEETT= (unsigned short*)p; p += (size_t)F_DIM*F_DIM*2;  //  0.5 MB
  unsigned char* SEEB8 = (unsigned char*)p;  p += (size_t)F_DIM*F_DIM;    //  0.26 MB
  // aliases
  unsigned short* XLN  = (unsigned short*)ZV;      // 16.8 of 33.6 MB
  unsigned char* OUT8  = (unsigned char*)VECSb;    //  8.4 of 16.8 MB
  float2* PART         = (float2*)Hb;              // 32.8 of 67.1 MB

  // independent prep
  cast_emb<<<4096, 256, 0, stream>>>(emb, EMBb, EMB8);
  cast_w<<<2048, 256, 0, stream>>>(W_in,  WINb,  H_DIM*F_DIM);
  cast_w<<<2048, 256, 0, stream>>>(W_out, WOUTb, F_DIM*H_DIM);
  prep_see<<<512, 256, 0, stream>>>(see, SEETT, SEEB8);
  gather_vecs<<<ROWS/4, 256, 0, stream>>>(emb, inp, VECSb);

  // ZV = pack(vecs, vecs @ see_top + bias)  — direct packed epilogue (MODE 5)
  gemm_bt<5><<<128*4, 256, 0, stream>>>(VECSb, SEETT, bias, nullptr, nullptr,
                                        VECSb, ZV, ROWS, F_DIM, F_DIM, 128, 4);

  // batch-parallel recurrence: 4 WGs, fp8-resident weights, no inter-block sync
  recurrence_batch<<<4, 512, 0, stream>>>(ZV, SEEB8, CONTB);

  // downstream
  ln_kernel<<<ROWS/4, 256, 0, stream>>>(CONTB, ln_g, ln_b, XLN);
  gemm_bt<0><<<128*16, 256, 0, stream>>>(XLN,  WINb,  b_in,  Hb,   nullptr,
                                         nullptr, nullptr, ROWS, H_DIM, F_DIM, 128, 16);
  gemm_bt<4><<<128*4,  256, 0, stream>>>(Hb,   WOUTb, b_out, OUTb, OUT8,
                                         nullptr, nullptr, ROWS, F_DIM, H_DIM, 128, 4);
  tlogit_kernel<<<ROWS/4, 256, 0, stream>>>(OUTb, EMBb, tgt, TL);
  gemm_f8_logits<<<128*NT_LOG, 256, 0, stream>>>(OUT8, EMB8, PART, ROWS, V_DIM, F_DIM, 128, NT_LOG);
  lse_kernel<<<ROWS/4, 256, 0, stream>>>(PART, TL, NLL);
  loss_kernel<<<1, 256, 0, stream>>>(NLL, tgt, (float*)d_out);
}

// Round 9
// 1777.416 us; speedup vs baseline: 7.8533x; 1.0823x over previous
//
#include <hip/hip_runtime.h>
#include <hip/hip_fp8.h>

#define F_DIM 512
#define H_DIM 2048
#define V_DIM 32000
#define B_DIM 64
#define S_DIM 256
#define ROWS (S_DIM*B_DIM)          // 16384
#define NT_LOG 250                  // 32000/128
#define SCALE 0.04419417382415922f  // 1/sqrt(512)

typedef __attribute__((ext_vector_type(8))) short  short8;
typedef __attribute__((ext_vector_type(4))) float  floatx4;

static __device__ inline unsigned short f2bf(float x){
  unsigned int u = __float_as_uint(x);
  u += 0x7fffu + ((u >> 16) & 1u);           // RNE
  return (unsigned short)(u >> 16);
}
static __device__ inline float bf2f(unsigned short u){
  return __uint_as_float(((unsigned int)u) << 16);
}
static __device__ inline unsigned char f2fp8(float x){
  __hip_fp8_e4m3 q(x);
  return q.__x;
}
static __device__ inline float wsum(float v){
  #pragma unroll
  for(int m = 32; m > 0; m >>= 1) v += __shfl_xor(v, m);
  return v;
}
static __device__ inline void load_lds16(const void* g, void* l){
  __builtin_amdgcn_global_load_lds((const __attribute__((address_space(1))) void*)g,
                                   (__attribute__((address_space(3))) void*)l, 16, 0, 0);
}

// ---------------- casts ----------------
__global__ __launch_bounds__(256) void cast_w(const float* __restrict__ src,
                                              unsigned short* __restrict__ dst, int n){
  int i = blockIdx.x*256 + threadIdx.x;
  int stride = gridDim.x*256;
  for(; i < n; i += stride) dst[i] = f2bf(src[i]);
}
// emb -> bf16 (for tlogit) + fp8 (for logits GEMM), PAD row zeroed
__global__ __launch_bounds__(256) void cast_emb(const float* __restrict__ src,
    unsigned short* __restrict__ dst, unsigned char* __restrict__ d8){
  int i = blockIdx.x*256 + threadIdx.x;
  int stride = gridDim.x*256;
  for(; i < V_DIM*F_DIM; i += stride){
    float v = (i < F_DIM) ? 0.f : src[i];
    dst[i] = f2bf(v);
    d8[i] = f2fp8(v);
  }
}

// ---------------- prep: see_top^T bf16 (for Z gemm) + see_bot^T fp8 ----------
__global__ __launch_bounds__(256) void prep_see(const float* __restrict__ see,
    unsigned short* __restrict__ TT, unsigned char* __restrict__ B8){
  int n = blockIdx.x;
  for(int k = threadIdx.x; k < 512; k += 256){
    TT[n*512 + k] = f2bf(see[(long)k*512 + n]);
    B8[n*512 + k] = f2fp8(see[(long)(512+k)*512 + n]);
  }
}

// ---------------- gather embedding rows per (t,b), bf16; row = t*64+b -------
__global__ __launch_bounds__(256) void gather_vecs(const float* __restrict__ emb,
    const int* __restrict__ inp, unsigned short* __restrict__ V){
  long row = (long)blockIdx.x*4 + (threadIdx.x >> 6);
  int l = threadIdx.x & 63;
  int t = (int)(row >> 6), b = (int)(row & 63);
  int idx = inp[b*S_DIM + t];
  short8 o;
  if (idx == 0){
    #pragma unroll
    for(int i=0;i<8;i++) o[i] = 0;
  } else {
    const float* e = emb + (long)idx*F_DIM + l*8;
    float4 a = *(const float4*)e;
    float4 bq = *(const float4*)(e + 4);
    o[0]=(short)f2bf(a.x); o[1]=(short)f2bf(a.y); o[2]=(short)f2bf(a.z); o[3]=(short)f2bf(a.w);
    o[4]=(short)f2bf(bq.x);o[5]=(short)f2bf(bq.y);o[6]=(short)f2bf(bq.z);o[7]=(short)f2bf(bq.w);
  }
  *(short8*)(V + row*F_DIM + l*8) = o;
}

// ---------------- batch-parallel recurrence, fp8-resident weights ----------
__global__ __launch_bounds__(512, 1) void recurrence_batch(
    const unsigned int* __restrict__ ZV,       // [16384,512] (vec<<16)|z  bf16 pair
    const unsigned char* __restrict__ W8,      // seeBotT fp8 [n=512][k=512]
    unsigned short* __restrict__ CONTB)        // [256][64][512] bf16 state history
{
  __shared__ unsigned char stt[2][16][520];    // 520 = 8B-aligned pad

  const int tid = threadIdx.x;
  const int w  = tid >> 6;       // wave 0..7 -> cols w*64..
  const int l  = tid & 63;
  const int rl = l & 15, rq = l >> 4;
  const int wg = blockIdx.x;     // batch rows wg*16..
  const int colb = w*64;

  // persistent fp8 B fragments: [k-chunk][n-tile], 2 VGPRs each = 128 VGPRs
  long Bfr[16][4];
  #pragma unroll
  for(int c=0;c<16;c++)
    #pragma unroll
    for(int tl=0;tl<4;tl++)
      Bfr[c][tl] = *(const long*)(W8 + (long)(colb + tl*16 + rl)*512 + c*32 + rq*8);

  float s_old[16];
  #pragma unroll
  for(int i=0;i<16;i++) s_old[i] = 0.f;

  unsigned int zv[16];
  #pragma unroll
  for(int tl=0;tl<4;tl++)
    #pragma unroll
    for(int r=0;r<4;r++)
      zv[tl*4+r] = ZV[(long)(wg*16 + rq*4 + r)*512 + colb + tl*16 + rl];

  for(int t = 0; t < S_DIM; t++){
    __syncthreads();   // prev-step LDS writes visible; prev reads done

    floatx4 acc[4];
    #pragma unroll
    for(int tl=0;tl<4;tl++) acc[tl] = (floatx4)0.f;

    if (t > 0){
      const unsigned char* sb = &stt[(t-1)&1][0][0];
      #pragma unroll
      for(int c=0;c<16;c++){
        long a = *(const long*)(sb + rl*520 + c*32 + rq*8);
        #pragma unroll
        for(int tl=0;tl<4;tl++)
          acc[tl] = __builtin_amdgcn_mfma_f32_16x16x32_fp8_fp8(a, Bfr[c][tl], acc[tl], 0, 0, 0);
      }
    }

    unsigned int zvn[16];
    if (t+1 < S_DIM){
      #pragma unroll
      for(int tl=0;tl<4;tl++)
        #pragma unroll
        for(int r=0;r<4;r++)
          zvn[tl*4+r] = ZV[((long)(t+1)*64 + wg*16 + rq*4 + r)*512 + colb + tl*16 + rl];
    }

    unsigned short* cw = CONTB + ((long)t*64 + wg*16)*512;
    unsigned char* sw = &stt[t&1][0][0];
    #pragma unroll
    for(int tl=0;tl<4;tl++)
      #pragma unroll
      for(int r=0;r<4;r++){
        int m = rq*4 + r;
        int col = colb + tl*16 + rl;
        unsigned int p = zv[tl*4+r];
        float z = bf2f((unsigned short)(p & 0xffffu)) + acc[tl][r];
        float g = 1.f/(1.f + __expf(-z));
        float v = bf2f((unsigned short)(p >> 16));
        float s = s_old[tl*4+r]*g + v*(1.f - g);
        s_old[tl*4+r] = s;
        cw[(long)m*512 + col] = f2bf(s);
        sw[m*520 + col] = f2fp8(s);
      }

    #pragma unroll
    for(int i=0;i<16;i++) zv[i] = zvn[i];
  }
}

// ---------------- layernorm (bf16 in) + bf16 cast; 1 row per wave ----------------
__global__ __launch_bounds__(256) void ln_kernel(const unsigned short* __restrict__ contb,
    const float* __restrict__ lg, const float* __restrict__ lb,
    unsigned short* __restrict__ xln)
{
  const int wid = threadIdx.x >> 6, l = threadIdx.x & 63;
  const long row = (long)blockIdx.x*4 + wid;
  short8 xv = *(const short8*)(contb + row*F_DIM + l*8);
  float v[8];
  #pragma unroll
  for(int i=0;i<8;i++) v[i] = bf2f((unsigned short)xv[i]);
  float s = 0.f;
  #pragma unroll
  for(int i=0;i<8;i++) s += v[i];
  s = wsum(s);
  float mu = s * (1.f/512.f);
  float q = 0.f;
  #pragma unroll
  for(int i=0;i<8;i++){ float d = v[i]-mu; q += d*d; }
  q = wsum(q);
  float rs = rsqrtf(q*(1.f/512.f) + 1e-5f);
  short8 o;
  #pragma unroll
  for(int i=0;i<8;i++)
    o[i] = (short)f2bf((v[i]-mu)*rs*lg[l*8+i] + lb[l*8+i]);
  *(short8*)(xln + row*F_DIM + l*8) = o;
}

// ---------------- bf16 MFMA GEMM: C[M,N] = A[M,K] * B[N,K]^T ----------------
// XOR-swizzled LDS (r6: conflicts 1.97e8 -> 0).
// MODE 0: +bias, relu, store bf16.
// MODE 4: +bias, store bf16 AND fp8 (logits-GEMM input).
// MODE 5: +bias, store packed ZV word: (Vsrc<<16)|bf16(v)  (recurrence input).
template<int MODE>
__global__ __launch_bounds__(256) void gemm_bt(
    const unsigned short* __restrict__ A,
    const unsigned short* __restrict__ Bm,
    const float* __restrict__ bias,
    unsigned short* __restrict__ C,
    unsigned char* __restrict__ C8,
    const unsigned short* __restrict__ Vsrc,
    unsigned int* __restrict__ ZVout,
    int M, int N, int K, int tiles_m, int tiles_n)
{
  __shared__ short As[128*64];
  __shared__ short Bs[128*64];

  const int bid = blockIdx.x;
  const int mt = bid % tiles_m;
  const int nt = bid / tiles_m;
  const long m0 = (long)mt * 128;
  const long n0 = (long)nt * 128;
  const int tid = threadIdx.x;
  const int l = tid & 63;
  const int wid = tid >> 6;
  const int wr = wid >> 1, wc = wid & 1;
  const int rl = l & 15, rq = l >> 4;

  const short* Ag = (const short*)A + m0 * K;
  const short* Bg = (const short*)Bm + n0 * K;
  const int grow = tid >> 3;   // 0..31
  const int kp = tid & 7;      // 0..7
  const int ksw = (kp ^ (grow & 7)) * 8;   // swizzled global chunk offset (shorts)

  floatx4 acc[4][4];
  #pragma unroll
  for(int i=0;i<4;i++)
    #pragma unroll
    for(int j=0;j<4;j++) acc[i][j] = (floatx4)0.f;

  for(int k0 = 0; k0 < K; k0 += 64){
    __syncthreads();
    #pragma unroll
    for(int ro = 0; ro < 128; ro += 32){
      load_lds16(Ag + (long)(ro + grow)*K + k0 + ksw, (void*)(As + (ro+grow)*64 + kp*8));
      load_lds16(Bg + (long)(ro + grow)*K + k0 + ksw, (void*)(Bs + (ro+grow)*64 + kp*8));
    }
    __syncthreads();
    #pragma unroll
    for(int kb = 0; kb < 64; kb += 32){
      const int cb = kb >> 3;              // base chunk: 0 or 4
      const int cl = ((cb + rq) ^ (rl & 7)) * 8;   // swizzled LDS chunk (shorts)
      short8 af[4], bfr[4];
      #pragma unroll
      for(int i=0;i<4;i++) af[i]  = *(const short8*)(As + (wr*64 + i*16 + rl)*64 + cl);
      #pragma unroll
      for(int j=0;j<4;j++) bfr[j] = *(const short8*)(Bs + (wc*64 + j*16 + rl)*64 + cl);
      #pragma unroll
      for(int i=0;i<4;i++)
        #pragma unroll
        for(int j=0;j<4;j++)
          acc[i][j] = __builtin_amdgcn_mfma_f32_16x16x32_bf16(af[i], bfr[j], acc[i][j], 0, 0, 0);
    }
  }

  const long mb = m0 + wr*64;
  const long nb = n0 + wc*64;
  #pragma unroll
  for(int j=0;j<4;j++){
    float bj = bias[nb + j*16 + rl];
    #pragma unroll
    for(int i=0;i<4;i++){
      #pragma unroll
      for(int r=0;r<4;r++){
        float v = acc[i][j][r] + bj;
        if (MODE == 0) v = fmaxf(v, 0.f);
        long idx = (mb + i*16 + rq*4 + r)*N + nb + j*16 + rl;
        if (MODE == 5){
          ZVout[idx] = ((unsigned)Vsrc[idx] << 16) | (unsigned)f2bf(v);
        } else {
          C[idx] = f2bf(v);
          if (MODE == 4) C8[idx] = f2fp8(v);
        }
      }
    }
  }
}

// ---------------- fp8 logits GEMM + online-softmax partials ----------------
// Swizzle v2 (r8 lesson): ds_read_b64 issues in 16-lane phases (rq const per
// phase), so the slot permutation must spread WITHIN a phase. Bank half is
// pinned by row parity (64 B rows); slot = c ^ ((rl>>1)&3) puts the 8 same-
// parity lanes of a phase on all 4 slots (2/slot = 2-way = free). r8's
// c ^ (rl&3) left even-rl lanes on 2 slots -> 4-way/phase -> 1.97e8 conflicts.
__global__ __launch_bounds__(256) void gemm_f8_logits(
    const unsigned char* __restrict__ A8,
    const unsigned char* __restrict__ B8,
    float2* __restrict__ part,
    int M, int N, int K, int tiles_m, int tiles_n)
{
  __shared__ unsigned char As8[128*64];
  __shared__ unsigned char Bs8[128*64];
  __shared__ float sm[2][64][2][2];

  const int bid = blockIdx.x;
  const int mt = bid % tiles_m;
  const int nt = bid / tiles_m;
  const long m0 = (long)mt * 128;
  const long n0 = (long)nt * 128;
  const int tid = threadIdx.x;
  const int l = tid & 63;
  const int wid = tid >> 6;
  const int wr = wid >> 1, wc = wid & 1;
  const int rl = l & 15, rq = l >> 4;

  const unsigned char* Ag = A8 + m0 * K;
  const unsigned char* Bg = B8 + n0 * K;
  const int grow = tid >> 2;                      // 0..63
  const int kp = tid & 3;                         // 0..3
  const int ksw = (kp ^ ((grow >> 1) & 3)) << 4;  // swizzled global chunk (bytes)

  floatx4 acc[4][4];
  #pragma unroll
  for(int i=0;i<4;i++)
    #pragma unroll
    for(int j=0;j<4;j++) acc[i][j] = (floatx4)0.f;

  for(int k0 = 0; k0 < K; k0 += 64){
    __syncthreads();
    #pragma unroll
    for(int ro = 0; ro < 128; ro += 64){
      load_lds16(Ag + (long)(ro + grow)*K + k0 + ksw, (void*)(As8 + (ro+grow)*64 + kp*16));
      load_lds16(Bg + (long)(ro + grow)*K + k0 + ksw, (void*)(Bs8 + (ro+grow)*64 + kp*16));
    }
    __syncthreads();
    const int rsw = (rl >> 1) & 3;
    #pragma unroll
    for(int kb = 0; kb < 64; kb += 32){
      const int c = (kb >> 4) + (rq >> 1);
      const int lo = (rq & 1) * 8;
      const int cl = ((c ^ rsw) << 4) + lo;   // swizzled LDS byte offset
      long af[4], bfr[4];
      #pragma unroll
      for(int i=0;i<4;i++) af[i]  = *(const long*)(As8 + (wr*64 + i*16 + rl)*64 + cl);
      #pragma unroll
      for(int j=0;j<4;j++) bfr[j] = *(const long*)(Bs8 + (wc*64 + j*16 + rl)*64 + cl);
      #pragma unroll
      for(int i=0;i<4;i++)
        #pragma unroll
        for(int j=0;j<4;j++)
          acc[i][j] = __builtin_amdgcn_mfma_f32_16x16x32_fp8_fp8(af[i], bfr[j], acc[i][j], 0, 0, 0);
    }
  }

  // online-softmax partials per 128-col tile
  #pragma unroll
  for(int i=0;i<4;i++){
    #pragma unroll
    for(int r=0;r<4;r++){
      float mx = -3.4e38f;
      #pragma unroll
      for(int j=0;j<4;j++) mx = fmaxf(mx, acc[i][j][r]);
      #pragma unroll
      for(int d=1; d<16; d<<=1) mx = fmaxf(mx, __shfl_xor(mx, d));
      float ms = mx * SCALE;
      float sv = 0.f;
      #pragma unroll
      for(int j=0;j<4;j++) sv += expf(acc[i][j][r]*SCALE - ms);
      #pragma unroll
      for(int d=1; d<16; d<<=1) sv += __shfl_xor(sv, d);
      if (rl == 0){
        int rowl = i*16 + rq*4 + r;
        sm[wr][rowl][wc][0] = ms;
        sm[wr][rowl][wc][1] = sv;
      }
    }
  }
  __syncthreads();
  if (tid < 128){
    int wr2 = tid >> 6, rowl = tid & 63;
    float ma = sm[wr2][rowl][0][0], sa = sm[wr2][rowl][0][1];
    float mb2= sm[wr2][rowl][1][0], sb = sm[wr2][rowl][1][1];
    float Mn = fmaxf(ma, mb2);
    float Ln = sa*expf(ma - Mn) + sb*expf(mb2 - Mn);
    float2 o; o.x = Mn; o.y = Ln;
    part[(m0 + wr2*64 + rowl)*tiles_n + nt] = o;
  }
}

// ---------------- target logit (bf16 inputs — more accurate than fp8 LSE side) --
__global__ __launch_bounds__(256) void tlogit_kernel(const unsigned short* __restrict__ outb,
    const unsigned short* __restrict__ embb, const int* __restrict__ tgt,
    float* __restrict__ TL)
{
  long gw = (long)blockIdx.x*4 + (threadIdx.x >> 6);
  int l = threadIdx.x & 63;
  int t = (int)(gw >> 6), b = (int)(gw & 63);
  int tg = tgt[b*S_DIM + t];
  const unsigned short* o = outb + gw*F_DIM;
  const unsigned short* e = embb + (long)tg*F_DIM;
  short8 ov = *(const short8*)(o + l*8);
  short8 ev = *(const short8*)(e + l*8);
  float s = 0.f;
  #pragma unroll
  for(int i=0;i<8;i++) s += bf2f((unsigned short)ov[i]) * bf2f((unsigned short)ev[i]);
  s = wsum(s);
  if (l == 0) TL[gw] = s * SCALE;
}

// ---------------- merge partials -> nll ----------------
__global__ __launch_bounds__(256) void lse_kernel(const float2* __restrict__ part,
    const float* __restrict__ TL, float* __restrict__ nll)
{
  long row = (long)blockIdx.x*4 + (threadIdx.x >> 6);
  int l = threadIdx.x & 63;
  float M = -3.4e38f, L = 0.f;
  for(int c = l; c < NT_LOG; c += 64){
    float2 pv = part[row*NT_LOG + c];
    float Mn = fmaxf(M, pv.x);
    L = L*expf(M - Mn) + pv.y*expf(pv.x - Mn);
    M = Mn;
  }
  #pragma unroll
  for(int d=1; d<64; d<<=1){
    float Mo = __shfl_xor(M, d), Lo = __shfl_xor(L, d);
    float Mn = fmaxf(M, Mo);
    L = L*expf(M - Mn) + Lo*expf(Mo - Mn);
    M = Mn;
  }
  if (l == 0) nll[row] = (M + logf(L)) - TL[row];
}

// ---------------- final loss ----------------
__global__ __launch_bounds__(256) void loss_kernel(const float* __restrict__ nll,
    const int* __restrict__ tgt, float* __restrict__ out)
{
  int t = threadIdx.x;
  float s = 0.f; int cnt = 0;
  for(int b = 0; b < B_DIM; b++){
    int v = tgt[b*S_DIM + t];
    if (v != 0){ s += nll[(long)t*B_DIM + b]; cnt++; }
  }
  float li = s / fmaxf((float)cnt, 1.f);
  li = wsum(li);
  __shared__ float red[4];
  if ((t & 63) == 0) red[t >> 6] = li;
  __syncthreads();
  if (t == 0) out[0] = (red[0]+red[1]+red[2]+red[3]) * (1.f/256.f);
}

extern "C" void kernel_launch(void* const* d_in, const int* in_sizes, int n_in,
                              void* d_out, int out_size, void* d_ws, size_t ws_size,
                              hipStream_t stream)
{
  const int*   inp   = (const int*)d_in[0];
  const int*   tgt   = (const int*)d_in[1];
  const float* see   = (const float*)d_in[2];
  const float* bias  = (const float*)d_in[3];
  const float* W_in  = (const float*)d_in[4];
  const float* b_in  = (const float*)d_in[5];
  const float* W_out = (const float*)d_in[6];
  const float* b_out = (const float*)d_in[7];
  const float* ln_g  = (const float*)d_in[8];
  const float* ln_b  = (const float*)d_in[9];
  const float* emb   = (const float*)d_in[10];

  // Workspace plan — peak ~205 MB (r7's 280 MB overflowed the ~256 MB pool).
  // Aliases safe by stream order:
  //   XLN  aliases ZV     (ZV dead after recurrence; XLN born at ln)
  //   OUT8 aliases VECSb  (VECSb dead after Z-gemm; OUT8 born at FFN2)
  //   PART aliases Hb     (Hb dead after FFN2; PART born at logits gemm)
  char* p = (char*)d_ws;
  unsigned short* CONTB= (unsigned short*)p; p += (size_t)ROWS*F_DIM*2;   // 16.8 MB
  unsigned short* Hb   = (unsigned short*)p; p += (size_t)ROWS*H_DIM*2;   // 67.1 MB
  unsigned short* OUTb = (unsigned short*)p; p += (size_t)ROWS*F_DIM*2;   // 16.8 MB
  unsigned short* EMBb = (unsigned short*)p; p += (size_t)V_DIM*F_DIM*2;  // 32.8 MB
  unsigned char* EMB8  = (unsigned char*)p;  p += (size_t)V_DIM*F_DIM;    // 16.4 MB
  unsigned short* WINb = (unsigned short*)p; p += (size_t)H_DIM*F_DIM*2;  //  2.1 MB
  unsigned short* WOUTb= (unsigned short*)p; p += (size_t)F_DIM*H_DIM*2;  //  2.1 MB
  float* TL            = (float*)p;          p += (size_t)ROWS*4;
  float* NLL           = (float*)p;          p += (size_t)ROWS*4;
  unsigned short* VECSb= (unsigned short*)p; p += (size_t)ROWS*F_DIM*2;   // 16.8 MB
  unsigned int* ZV     = (unsigned int*)p;   p += (size_t)ROWS*F_DIM*4;   // 33.6 MB
  unsigned short* SEETT= (unsigned short*)p; p += (size_t)F_DIM*F_DIM*2;  //  0.5 MB
  unsigned char* SEEB8 = (unsigned char*)p;  p += (size_t)F_DIM*F_DIM;    //  0.26 MB
  // aliases
  unsigned short* XLN  = (unsigned short*)ZV;      // 16.8 of 33.6 MB
  unsigned char* OUT8  = (unsigned char*)VECSb;    //  8.4 of 16.8 MB
  float2* PART         = (float2*)Hb;              // 32.8 of 67.1 MB

  // independent prep
  cast_emb<<<4096, 256, 0, stream>>>(emb, EMBb, EMB8);
  cast_w<<<2048, 256, 0, stream>>>(W_in,  WINb,  H_DIM*F_DIM);
  cast_w<<<2048, 256, 0, stream>>>(W_out, WOUTb, F_DIM*H_DIM);
  prep_see<<<512, 256, 0, stream>>>(see, SEETT, SEEB8);
  gather_vecs<<<ROWS/4, 256, 0, stream>>>(emb, inp, VECSb);

  // ZV = pack(vecs, vecs @ see_top + bias)  — direct packed epilogue (MODE 5)
  gemm_bt<5><<<128*4, 256, 0, stream>>>(VECSb, SEETT, bias, nullptr, nullptr,
                                        VECSb, ZV, ROWS, F_DIM, F_DIM, 128, 4);

  // batch-parallel recurrence: 4 WGs, fp8-resident weights, no inter-block sync
  recurrence_batch<<<4, 512, 0, stream>>>(ZV, SEEB8, CONTB);

  // downstream
  ln_kernel<<<ROWS/4, 256, 0, stream>>>(CONTB, ln_g, ln_b, XLN);
  gemm_bt<0><<<128*16, 256, 0, stream>>>(XLN,  WINb,  b_in,  Hb,   nullptr,
                                         nullptr, nullptr, ROWS, H_DIM, F_DIM, 128, 16);
  gemm_bt<4><<<128*4,  256, 0, stream>>>(Hb,   WOUTb, b_out, OUTb, OUT8,
                                         nullptr, nullptr, ROWS, F_DIM, H_DIM, 128, 4);
  tlogit_kernel<<<ROWS/4, 256, 0, stream>>>(OUTb, EMBb, tgt, TL);
  gemm_f8_logits<<<128*NT_LOG, 256, 0, stream>>>(OUT8, EMB8, PART, ROWS, V_DIM, F_DIM, 128, NT_LOG);
  lse_kernel<<<ROWS/4, 256, 0, stream>>>(PART, TL, NLL);
  loss_kernel<<<1, 256, 0, stream>>>(NLL, tgt, (float*)d_out);
}

// Round 10
// 1572.757 us; speedup vs baseline: 8.8753x; 1.1301x over previous
//
#include <hip/hip_runtime.h>
#include <hip/hip_fp8.h>

#define F_DIM 512
#define H_DIM 2048
#define V_DIM 32000
#define B_DIM 64
#define S_DIM 256
#define ROWS (S_DIM*B_DIM)          // 16384
#define NT_LOG 250                  // 32000/128
#define SCALE 0.04419417382415922f  // 1/sqrt(512)
#define LSE_OFF 40.0f               // fixed softmax offset; |logit*SCALE| ~ O(8)

typedef __attribute__((ext_vector_type(8))) short  short8;
typedef __attribute__((ext_vector_type(4))) float  floatx4;

static __device__ inline unsigned short f2bf(float x){
  unsigned int u = __float_as_uint(x);
  u += 0x7fffu + ((u >> 16) & 1u);           // RNE
  return (unsigned short)(u >> 16);
}
static __device__ inline float bf2f(unsigned short u){
  return __uint_as_float(((unsigned int)u) << 16);
}
static __device__ inline unsigned char f2fp8(float x){
  __hip_fp8_e4m3 q(x);
  return q.__x;
}
// fp8-buffer bank swizzle: within each 64-B segment of a row, granule g (8 B)
// is stored at chunk=(g>>1)^((row>>1)&3), lob=(g&1)^((row>>3)&1). With this,
// a 16-lane ds_read_b64 phase in gemm_f8_logits covers all 32 banks exactly
// once (r9 lesson: staging's 16-B atomicity forbids fixing lob at load time).
static __device__ inline int sw8(int row, int col){
  int g = (col >> 3) & 7;
  int chunk = ((g >> 1) ^ ((row >> 1) & 3));
  int lob = (g & 1) ^ ((row >> 3) & 1);
  return (col & ~63) | (chunk << 4) | (lob << 3) | (col & 7);
}
static __device__ inline float wsum(float v){
  #pragma unroll
  for(int m = 32; m > 0; m >>= 1) v += __shfl_xor(v, m);
  return v;
}
static __device__ inline void load_lds16(const void* g, void* l){
  __builtin_amdgcn_global_load_lds((const __attribute__((address_space(1))) void*)g,
                                   (__attribute__((address_space(3))) void*)l, 16, 0, 0);
}

// ---------------- casts ----------------
__global__ __launch_bounds__(256) void cast_w(const float* __restrict__ src,
                                              unsigned short* __restrict__ dst, int n){
  int i = blockIdx.x*256 + threadIdx.x;
  int stride = gridDim.x*256;
  for(; i < n; i += stride) dst[i] = f2bf(src[i]);
}
// emb -> bf16 (for tlogit) + fp8 bank-swizzled (for logits GEMM), PAD row zeroed
__global__ __launch_bounds__(256) void cast_emb(const float* __restrict__ src,
    unsigned short* __restrict__ dst, unsigned char* __restrict__ d8){
  int i = blockIdx.x*256 + threadIdx.x;
  int stride = gridDim.x*256;
  for(; i < V_DIM*F_DIM; i += stride){
    float v = (i < F_DIM) ? 0.f : src[i];
    dst[i] = f2bf(v);
    int row = i >> 9, col = i & 511;
    d8[(long)row*512 + sw8(row, col)] = f2fp8(v);
  }
}

// ---------------- prep: see_top^T bf16 (for Z gemm) + see_bot^T fp8 ----------
__global__ __launch_bounds__(256) void prep_see(const float* __restrict__ see,
    unsigned short* __restrict__ TT, unsigned char* __restrict__ B8){
  int n = blockIdx.x;
  for(int k = threadIdx.x; k < 512; k += 256){
    TT[n*512 + k] = f2bf(see[(long)k*512 + n]);
    B8[n*512 + k] = f2fp8(see[(long)(512+k)*512 + n]);
  }
}

// ---------------- gather embedding rows per (t,b), bf16; row = t*64+b -------
__global__ __launch_bounds__(256) void gather_vecs(const float* __restrict__ emb,
    const int* __restrict__ inp, unsigned short* __restrict__ V){
  long row = (long)blockIdx.x*4 + (threadIdx.x >> 6);
  int l = threadIdx.x & 63;
  int t = (int)(row >> 6), b = (int)(row & 63);
  int idx = inp[b*S_DIM + t];
  short8 o;
  if (idx == 0){
    #pragma unroll
    for(int i=0;i<8;i++) o[i] = 0;
  } else {
    const float* e = emb + (long)idx*F_DIM + l*8;
    float4 a = *(const float4*)e;
    float4 bq = *(const float4*)(e + 4);
    o[0]=(short)f2bf(a.x); o[1]=(short)f2bf(a.y); o[2]=(short)f2bf(a.z); o[3]=(short)f2bf(a.w);
    o[4]=(short)f2bf(bq.x);o[5]=(short)f2bf(bq.y);o[6]=(short)f2bf(bq.z);o[7]=(short)f2bf(bq.w);
  }
  *(short8*)(V + row*F_DIM + l*8) = o;
}

// ---------------- batch-parallel recurrence, fp8-resident weights ----------
__global__ __launch_bounds__(512, 1) void recurrence_batch(
    const unsigned int* __restrict__ ZV,       // [16384,512] (vec<<16)|z  bf16 pair
    const unsigned char* __restrict__ W8,      // seeBotT fp8 [n=512][k=512]
    unsigned short* __restrict__ CONTB)        // [256][64][512] bf16 state history
{
  __shared__ unsigned char stt[2][16][520];    // 520 = 8B-aligned pad

  const int tid = threadIdx.x;
  const int w  = tid >> 6;       // wave 0..7 -> cols w*64..
  const int l  = tid & 63;
  const int rl = l & 15, rq = l >> 4;
  const int wg = blockIdx.x;     // batch rows wg*16..
  const int colb = w*64;

  // persistent fp8 B fragments: [k-chunk][n-tile], 2 VGPRs each = 128 VGPRs
  long Bfr[16][4];
  #pragma unroll
  for(int c=0;c<16;c++)
    #pragma unroll
    for(int tl=0;tl<4;tl++)
      Bfr[c][tl] = *(const long*)(W8 + (long)(colb + tl*16 + rl)*512 + c*32 + rq*8);

  float s_old[16];
  #pragma unroll
  for(int i=0;i<16;i++) s_old[i] = 0.f;

  unsigned int zv[16];
  #pragma unroll
  for(int tl=0;tl<4;tl++)
    #pragma unroll
    for(int r=0;r<4;r++)
      zv[tl*4+r] = ZV[(long)(wg*16 + rq*4 + r)*512 + colb + tl*16 + rl];

  for(int t = 0; t < S_DIM; t++){
    __syncthreads();   // prev-step LDS writes visible; prev reads done

    floatx4 acc[4];
    #pragma unroll
    for(int tl=0;tl<4;tl++) acc[tl] = (floatx4)0.f;

    if (t > 0){
      const unsigned char* sb = &stt[(t-1)&1][0][0];
      #pragma unroll
      for(int c=0;c<16;c++){
        long a = *(const long*)(sb + rl*520 + c*32 + rq*8);
        #pragma unroll
        for(int tl=0;tl<4;tl++)
          acc[tl] = __builtin_amdgcn_mfma_f32_16x16x32_fp8_fp8(a, Bfr[c][tl], acc[tl], 0, 0, 0);
      }
    }

    unsigned int zvn[16];
    if (t+1 < S_DIM){
      #pragma unroll
      for(int tl=0;tl<4;tl++)
        #pragma unroll
        for(int r=0;r<4;r++)
          zvn[tl*4+r] = ZV[((long)(t+1)*64 + wg*16 + rq*4 + r)*512 + colb + tl*16 + rl];
    }

    unsigned short* cw = CONTB + ((long)t*64 + wg*16)*512;
    unsigned char* sw = &stt[t&1][0][0];
    #pragma unroll
    for(int tl=0;tl<4;tl++)
      #pragma unroll
      for(int r=0;r<4;r++){
        int m = rq*4 + r;
        int col = colb + tl*16 + rl;
        unsigned int p = zv[tl*4+r];
        float z = bf2f((unsigned short)(p & 0xffffu)) + acc[tl][r];
        float g = 1.f/(1.f + __expf(-z));
        float v = bf2f((unsigned short)(p >> 16));
        float s = s_old[tl*4+r]*g + v*(1.f - g);
        s_old[tl*4+r] = s;
        cw[(long)m*512 + col] = f2bf(s);
        sw[m*520 + col] = f2fp8(s);
      }

    #pragma unroll
    for(int i=0;i<16;i++) zv[i] = zvn[i];
  }
}

// ---------------- layernorm (bf16 in) + bf16 cast; 1 row per wave ----------------
__global__ __launch_bounds__(256) void ln_kernel(const unsigned short* __restrict__ contb,
    const float* __restrict__ lg, const float* __restrict__ lb,
    unsigned short* __restrict__ xln)
{
  const int wid = threadIdx.x >> 6, l = threadIdx.x & 63;
  const long row = (long)blockIdx.x*4 + wid;
  short8 xv = *(const short8*)(contb + row*F_DIM + l*8);
  float v[8];
  #pragma unroll
  for(int i=0;i<8;i++) v[i] = bf2f((unsigned short)xv[i]);
  float s = 0.f;
  #pragma unroll
  for(int i=0;i<8;i++) s += v[i];
  s = wsum(s);
  float mu = s * (1.f/512.f);
  float q = 0.f;
  #pragma unroll
  for(int i=0;i<8;i++){ float d = v[i]-mu; q += d*d; }
  q = wsum(q);
  float rs = rsqrtf(q*(1.f/512.f) + 1e-5f);
  short8 o;
  #pragma unroll
  for(int i=0;i<8;i++)
    o[i] = (short)f2bf((v[i]-mu)*rs*lg[l*8+i] + lb[l*8+i]);
  *(short8*)(xln + row*F_DIM + l*8) = o;
}

// ---------------- bf16 MFMA GEMM: C[M,N] = A[M,K] * B[N,K]^T ----------------
// XOR-swizzled LDS (r6: conflicts 1.97e8 -> 0).
// MODE 0: +bias, relu, store bf16.
// MODE 4: +bias, store bf16 AND bank-swizzled fp8 (logits-GEMM input; N must be 512).
// MODE 5: +bias, store packed ZV word: (Vsrc<<16)|bf16(v)  (recurrence input).
template<int MODE>
__global__ __launch_bounds__(256) void gemm_bt(
    const unsigned short* __restrict__ A,
    const unsigned short* __restrict__ Bm,
    const float* __restrict__ bias,
    unsigned short* __restrict__ C,
    unsigned char* __restrict__ C8,
    const unsigned short* __restrict__ Vsrc,
    unsigned int* __restrict__ ZVout,
    int M, int N, int K, int tiles_m, int tiles_n)
{
  __shared__ short As[128*64];
  __shared__ short Bs[128*64];

  const int bid = blockIdx.x;
  const int mt = bid % tiles_m;
  const int nt = bid / tiles_m;
  const long m0 = (long)mt * 128;
  const long n0 = (long)nt * 128;
  const int tid = threadIdx.x;
  const int l = tid & 63;
  const int wid = tid >> 6;
  const int wr = wid >> 1, wc = wid & 1;
  const int rl = l & 15, rq = l >> 4;

  const short* Ag = (const short*)A + m0 * K;
  const short* Bg = (const short*)Bm + n0 * K;
  const int grow = tid >> 3;   // 0..31
  const int kp = tid & 7;      // 0..7
  const int ksw = (kp ^ (grow & 7)) * 8;   // swizzled global chunk offset (shorts)

  floatx4 acc[4][4];
  #pragma unroll
  for(int i=0;i<4;i++)
    #pragma unroll
    for(int j=0;j<4;j++) acc[i][j] = (floatx4)0.f;

  for(int k0 = 0; k0 < K; k0 += 64){
    __syncthreads();
    #pragma unroll
    for(int ro = 0; ro < 128; ro += 32){
      load_lds16(Ag + (long)(ro + grow)*K + k0 + ksw, (void*)(As + (ro+grow)*64 + kp*8));
      load_lds16(Bg + (long)(ro + grow)*K + k0 + ksw, (void*)(Bs + (ro+grow)*64 + kp*8));
    }
    __syncthreads();
    #pragma unroll
    for(int kb = 0; kb < 64; kb += 32){
      const int cb = kb >> 3;              // base chunk: 0 or 4
      const int cl = ((cb + rq) ^ (rl & 7)) * 8;   // swizzled LDS chunk (shorts)
      short8 af[4], bfr[4];
      #pragma unroll
      for(int i=0;i<4;i++) af[i]  = *(const short8*)(As + (wr*64 + i*16 + rl)*64 + cl);
      #pragma unroll
      for(int j=0;j<4;j++) bfr[j] = *(const short8*)(Bs + (wc*64 + j*16 + rl)*64 + cl);
      #pragma unroll
      for(int i=0;i<4;i++)
        #pragma unroll
        for(int j=0;j<4;j++)
          acc[i][j] = __builtin_amdgcn_mfma_f32_16x16x32_bf16(af[i], bfr[j], acc[i][j], 0, 0, 0);
    }
  }

  const long mb = m0 + wr*64;
  const long nb = n0 + wc*64;
  #pragma unroll
  for(int j=0;j<4;j++){
    float bj = bias[nb + j*16 + rl];
    #pragma unroll
    for(int i=0;i<4;i++){
      #pragma unroll
      for(int r=0;r<4;r++){
        float v = acc[i][j][r] + bj;
        if (MODE == 0) v = fmaxf(v, 0.f);
        int rowI = (int)(mb + i*16 + rq*4 + r);
        int colI = (int)(nb + j*16 + rl);
        long idx = (long)rowI*N + colI;
        if (MODE == 5){
          ZVout[idx] = ((unsigned)Vsrc[idx] << 16) | (unsigned)f2bf(v);
        } else {
          C[idx] = f2bf(v);
          if (MODE == 4) C8[(long)rowI*512 + sw8(rowI, colI)] = f2fp8(v);
        }
      }
    }
  }
}

// ---------------- fp8 logits GEMM + fixed-offset softmax partials ----------
// Inputs are PRE-BANK-SWIZZLED (sw8): staging is identity (global chunk kp ->
// LDS chunk kp), and a ds_read_b64 phase covers all 32 banks exactly once
// (zero conflicts; r9's in-kernel swizzle could only reach 2-way because
// global_load_lds can't split 16-B chunks). Epilogue: no per-tile max —
// fixed offset LSE_OFF (logit*SCALE is O(+-8)) -> partials are plain sums.
__global__ __launch_bounds__(256) void gemm_f8_logits(
    const unsigned char* __restrict__ A8,
    const unsigned char* __restrict__ B8,
    float* __restrict__ part,
    int M, int N, int K, int tiles_m, int tiles_n)
{
  __shared__ unsigned char As8[128*64];
  __shared__ unsigned char Bs8[128*64];
  __shared__ float sm2[2][64][2];

  const int bid = blockIdx.x;
  const int mt = bid % tiles_m;
  const int nt = bid / tiles_m;
  const long m0 = (long)mt * 128;
  const long n0 = (long)nt * 128;
  const int tid = threadIdx.x;
  const int l = tid & 63;
  const int wid = tid >> 6;
  const int wr = wid >> 1, wc = wid & 1;
  const int rl = l & 15, rq = l >> 4;

  const unsigned char* Ag = A8 + m0 * K;
  const unsigned char* Bg = B8 + n0 * K;
  const int grow = tid >> 2;               // 0..63
  const int kp = tid & 3;                  // 0..3

  floatx4 acc[4][4];
  #pragma unroll
  for(int i=0;i<4;i++)
    #pragma unroll
    for(int j=0;j<4;j++) acc[i][j] = (floatx4)0.f;

  // per-lane read swizzle pieces (row bits come from rl only; wave/tile bases
  // are multiples of 16 so their bits 1..3 contributions vanish)
  const int rsw = (rl >> 1) & 3;
  const int rhi = (rl >> 3) & 1;

  for(int k0 = 0; k0 < K; k0 += 64){
    __syncthreads();
    #pragma unroll
    for(int ro = 0; ro < 128; ro += 64){
      load_lds16(Ag + (long)(ro + grow)*K + k0 + kp*16, (void*)(As8 + (ro+grow)*64 + kp*16));
      load_lds16(Bg + (long)(ro + grow)*K + k0 + kp*16, (void*)(Bs8 + (ro+grow)*64 + kp*16));
    }
    __syncthreads();
    #pragma unroll
    for(int kb = 0; kb < 64; kb += 32){
      const int g = (kb >> 3) + rq;                  // logical granule 0..7
      const int cl = ((((g >> 1) ^ rsw)) << 4) | ((((g & 1) ^ rhi)) << 3);
      long af[4], bfr[4];
      #pragma unroll
      for(int i=0;i<4;i++) af[i]  = *(const long*)(As8 + (wr*64 + i*16 + rl)*64 + cl);
      #pragma unroll
      for(int j=0;j<4;j++) bfr[j] = *(const long*)(Bs8 + (wc*64 + j*16 + rl)*64 + cl);
      #pragma unroll
      for(int i=0;i<4;i++)
        #pragma unroll
        for(int j=0;j<4;j++)
          acc[i][j] = __builtin_amdgcn_mfma_f32_16x16x32_fp8_fp8(af[i], bfr[j], acc[i][j], 0, 0, 0);
    }
  }

  // fixed-offset sum-exp partials per 128-col tile
  #pragma unroll
  for(int i=0;i<4;i++){
    #pragma unroll
    for(int r=0;r<4;r++){
      float sv = 0.f;
      #pragma unroll
      for(int j=0;j<4;j++) sv += __expf(acc[i][j][r]*SCALE - LSE_OFF);
      #pragma unroll
      for(int d=1; d<16; d<<=1) sv += __shfl_xor(sv, d);
      if (rl == 0) sm2[wr][i*16 + rq*4 + r][wc] = sv;
    }
  }
  __syncthreads();
  if (tid < 128){
    int wr2 = tid >> 6, rowl = tid & 63;
    part[(m0 + wr2*64 + rowl)*tiles_n + nt] = sm2[wr2][rowl][0] + sm2[wr2][rowl][1];
  }
}

// ---------------- target logit (bf16 inputs) ----------------
__global__ __launch_bounds__(256) void tlogit_kernel(const unsigned short* __restrict__ outb,
    const unsigned short* __restrict__ embb, const int* __restrict__ tgt,
    float* __restrict__ TL)
{
  long gw = (long)blockIdx.x*4 + (threadIdx.x >> 6);
  int l = threadIdx.x & 63;
  int t = (int)(gw >> 6), b = (int)(gw & 63);
  int tg = tgt[b*S_DIM + t];
  const unsigned short* o = outb + gw*F_DIM;
  const unsigned short* e = embb + (long)tg*F_DIM;
  short8 ov = *(const short8*)(o + l*8);
  short8 ev = *(const short8*)(e + l*8);
  float s = 0.f;
  #pragma unroll
  for(int i=0;i<8;i++) s += bf2f((unsigned short)ov[i]) * bf2f((unsigned short)ev[i]);
  s = wsum(s);
  if (l == 0) TL[gw] = s * SCALE;
}

// ---------------- sum partials -> nll ----------------
__global__ __launch_bounds__(256) void lse_kernel(const float* __restrict__ part,
    const float* __restrict__ TL, float* __restrict__ nll)
{
  long row = (long)blockIdx.x*4 + (threadIdx.x >> 6);
  int l = threadIdx.x & 63;
  float S = 0.f;
  for(int c = l; c < NT_LOG; c += 64)
    S += part[row*NT_LOG + c];
  S = wsum(S);
  if (l == 0) nll[row] = (LSE_OFF + logf(S)) - TL[row];
}

// ---------------- final loss ----------------
__global__ __launch_bounds__(256) void loss_kernel(const float* __restrict__ nll,
    const int* __restrict__ tgt, float* __restrict__ out)
{
  int t = threadIdx.x;
  float s = 0.f; int cnt = 0;
  for(int b = 0; b < B_DIM; b++){
    int v = tgt[b*S_DIM + t];
    if (v != 0){ s += nll[(long)t*B_DIM + b]; cnt++; }
  }
  float li = s / fmaxf((float)cnt, 1.f);
  li = wsum(li);
  __shared__ float red[4];
  if ((t & 63) == 0) red[t >> 6] = li;
  __syncthreads();
  if (t == 0) out[0] = (red[0]+red[1]+red[2]+red[3]) * (1.f/256.f);
}

extern "C" void kernel_launch(void* const* d_in, const int* in_sizes, int n_in,
                              void* d_out, int out_size, void* d_ws, size_t ws_size,
                              hipStream_t stream)
{
  const int*   inp   = (const int*)d_in[0];
  const int*   tgt   = (const int*)d_in[1];
  const float* see   = (const float*)d_in[2];
  const float* bias  = (const float*)d_in[3];
  const float* W_in  = (const float*)d_in[4];
  const float* b_in  = (const float*)d_in[5];
  const float* W_out = (const float*)d_in[6];
  const float* b_out = (const float*)d_in[7];
  const float* ln_g  = (const float*)d_in[8];
  const float* ln_b  = (const float*)d_in[9];
  const float* emb   = (const float*)d_in[10];

  // Workspace plan — peak ~205 MB. Aliases safe by stream order:
  //   XLN  aliases ZV     (ZV dead after recurrence; XLN born at ln)
  //   OUT8 aliases VECSb  (VECSb dead after Z-gemm; OUT8 born at FFN2)
  //   PART aliases Hb     (Hb dead after FFN2; PART born at logits gemm)
  char* p = (char*)d_ws;
  unsigned short* CONTB= (unsigned short*)p; p += (size_t)ROWS*F_DIM*2;   // 16.8 MB
  unsigned short* Hb   = (unsigned short*)p; p += (size_t)ROWS*H_DIM*2;   // 67.1 MB
  unsigned short* OUTb = (unsigned short*)p; p += (size_t)ROWS*F_DIM*2;   // 16.8 MB
  unsigned short* EMBb = (unsigned short*)p; p += (size_t)V_DIM*F_DIM*2;  // 32.8 MB
  unsigned char* EMB8  = (unsigned char*)p;  p += (size_t)V_DIM*F_DIM;    // 16.4 MB
  unsigned short* WINb = (unsigned short*)p; p += (size_t)H_DIM*F_DIM*2;  //  2.1 MB
  unsigned short* WOUTb= (unsigned short*)p; p += (size_t)F_DIM*H_DIM*2;  //  2.1 MB
  float* TL            = (float*)p;          p += (size_t)ROWS*4;
  float* NLL           = (float*)p;          p += (size_t)ROWS*4;
  unsigned short* VECSb= (unsigned short*)p; p += (size_t)ROWS*F_DIM*2;   // 16.8 MB
  unsigned int* ZV     = (unsigned int*)p;   p += (size_t)ROWS*F_DIM*4;   // 33.6 MB
  unsigned short* SEETT= (unsigned short*)p; p += (size_t)F_DIM*F_DIM*2;  //  0.5 MB
  unsigned char* SEEB8 = (unsigned char*)p;  p += (size_t)F_DIM*F_DIM;    //  0.26 MB
  // aliases
  unsigned short* XLN  = (unsigned short*)ZV;      // 16.8 of 33.6 MB
  unsigned char* OUT8  = (unsigned char*)VECSb;    //  8.4 of 16.8 MB
  float* PART          = (float*)Hb;               // 16.4 of 67.1 MB

  // independent prep
  cast_emb<<<4096, 256, 0, stream>>>(emb, EMBb, EMB8);
  cast_w<<<2048, 256, 0, stream>>>(W_in,  WINb,  H_DIM*F_DIM);
  cast_w<<<2048, 256, 0, stream>>>(W_out, WOUTb, F_DIM*H_DIM);
  prep_see<<<512, 256, 0, stream>>>(see, SEETT, SEEB8);
  gather_vecs<<<ROWS/4, 256, 0, stream>>>(emb, inp, VECSb);

  // ZV = pack(vecs, vecs @ see_top + bias)  — direct packed epilogue (MODE 5)
  gemm_bt<5><<<128*4, 256, 0, stream>>>(VECSb, SEETT, bias, nullptr, nullptr,
                                        VECSb, ZV, ROWS, F_DIM, F_DIM, 128, 4);

  // batch-parallel recurrence: 4 WGs, fp8-resident weights, no inter-block sync
  recurrence_batch<<<4, 512, 0, stream>>>(ZV, SEEB8, CONTB);

  // downstream
  ln_kernel<<<ROWS/4, 256, 0, stream>>>(CONTB, ln_g, ln_b, XLN);
  gemm_bt<0><<<128*16, 256, 0, stream>>>(XLN,  WINb,  b_in,  Hb,   nullptr,
                                         nullptr, nullptr, ROWS, H_DIM, F_DIM, 128, 16);
  gemm_bt<4><<<128*4,  256, 0, stream>>>(Hb,   WOUTb, b_out, OUTb, OUT8,
                                         nullptr, nullptr, ROWS, F_DIM, H_DIM, 128, 4);
  tlogit_kernel<<<ROWS/4, 256, 0, stream>>>(OUTb, EMBb, tgt, TL);
  gemm_f8_logits<<<128*NT_LOG, 256, 0, stream>>>(OUT8, EMB8, PART, ROWS, V_DIM, F_DIM, 128, NT_LOG);
  lse_kernel<<<ROWS/4, 256, 0, stream>>>(PART, TL, NLL);
  loss_kernel<<<1, 256, 0, stream>>>(NLL, tgt, (float*)d_out);
}